// Round 10
// baseline (1557.649 us; speedup 1.0000x reference)
//
#include <hip/hip_runtime.h>
#include <hip/hip_bf16.h>

typedef unsigned short u16;
typedef unsigned char uchar;
typedef unsigned long long u64;
typedef float f32x4 __attribute__((ext_vector_type(4)));
typedef int i8v __attribute__((ext_vector_type(8)));

#define FDIM 2048
#define NBLK 256
#define NCELL 126

__device__ __forceinline__ u16 f2b(float x) {
    __hip_bfloat16 h = __float2bfloat16(x);
    return __builtin_bit_cast(u16, h);
}
__device__ __forceinline__ float b2f(u16 u) {
    __hip_bfloat16 h = __builtin_bit_cast(__hip_bfloat16, u);
    return __bfloat162float(h);
}
__device__ __forceinline__ float sigm(float x) { return 1.0f / (1.0f + __expf(-x)); }
__device__ __forceinline__ float tanh_f(float x) { return 1.0f - 2.0f / (__expf(2.0f * x) + 1.0f); }

// OCP e4m3 encode (RNE), saturate to 448.
__device__ __forceinline__ unsigned f2fp8(float x) {
    unsigned u = __builtin_bit_cast(unsigned, x);
    unsigned s = (u >> 24) & 0x80u;
    unsigned mag = u & 0x7fffffffu;
    if (mag >= 0x43E80000u) return s | 0x7Eu;
    int e = (int)(mag >> 23) - 127;
    if (e >= -6) {
        unsigned m = mag + 0x7FFFFu + ((mag >> 20) & 1u);
        unsigned e8 = (m >> 23) - 127 + 7;
        unsigned m3 = (m >> 20) & 7u;
        if (e8 >= 16u) return s | 0x7Eu;
        return s | (e8 << 3) | m3;
    }
    float ax = __builtin_bit_cast(float, mag);
    int d = (int)__builtin_rintf(ax * 512.0f);
    return s | (unsigned)d;
}

// e2m1 (fp4) quantize of v (|v|<=6 after scaling): returns 4-bit code
__device__ __forceinline__ unsigned q_e2m1(float v) {
    unsigned s = (v < 0.f) ? 8u : 0u;
    float a = fabsf(v);
    unsigned q;
    if (a < 0.25f) q = 0;
    else if (a < 0.75f) q = 1;
    else if (a < 1.25f) q = 2;
    else if (a < 1.75f) q = 3;
    else if (a < 2.5f)  q = 4;
    else if (a < 3.5f)  q = 5;
    else if (a < 5.0f)  q = 6;
    else q = 7;
    return s | q;
}

// ---------------- weight pack: fp32 -> MX fp4 (E8M0 per-32 scales), MFMA fragment order ----------
__global__ __launch_bounds__(256) void k_pack4(const float* __restrict__ W0, const float* __restrict__ W1,
                                               const float* __restrict__ W2, const float* __restrict__ W3,
                                               uchar* __restrict__ Wp4, uchar* __restrict__ scl) {
    __shared__ float lw[32][132];
    int idx = blockIdx.x;                 // [0, 256*4*16)
    int kt = idx & 15, mat = (idx >> 4) & 3, bl = idx >> 6;
    const float* src = mat == 0 ? W0 : mat == 1 ? W1 : mat == 2 ? W2 : W3;
    int tid = threadIdx.x;
    for (int i = tid; i < 32 * 32; i += 256) {
        int r = i >> 5, c4 = i & 31;
        const float* p = src + (size_t)((r >> 3) * 2048 + bl * 8 + (r & 7)) * 2048 + kt * 128 + c4 * 4;
        float4 v = *(const float4*)p;
        lw[r][c4 * 4 + 0] = v.x; lw[r][c4 * 4 + 1] = v.y;
        lw[r][c4 * 4 + 2] = v.z; lw[r][c4 * 4 + 3] = v.w;
    }
    __syncthreads();
    if (tid < 128) {
        int gp = tid >> 6, lane = tid & 63;
        int r = (2 * gp + ((lane & 15) >> 3)) * 8 + (lane & 7);
        int k0 = (lane >> 4) * 32;
        float mx = 0.f;
#pragma unroll
        for (int e = 0; e < 32; ++e) mx = fmaxf(mx, fabsf(lw[r][k0 + e]));
        int ee = -127;
        if (mx > 0.f) {
            ee = (int)ceilf(log2f(mx * (1.0f / 6.0f)));
            if (ee < -127) ee = -127;
            if (ee > 127) ee = 127;
        }
        float inv = exp2f((float)(-ee));
        unsigned wd[4];
#pragma unroll
        for (int d = 0; d < 4; ++d) {
            unsigned acc = 0;
#pragma unroll
            for (int bi = 0; bi < 4; ++bi) {
                float v0 = lw[r][k0 + d * 8 + 2 * bi] * inv;
                float v1 = lw[r][k0 + d * 8 + 2 * bi + 1] * inv;
                acc |= (q_e2m1(v0) << (bi * 8)) | (q_e2m1(v1) << (bi * 8 + 4));
            }
            wd[d] = acc;
        }
        size_t wo = (size_t)bl * 131072 + (((size_t)(mat * 2 + gp) * 16 + (size_t)kt) * 64 + lane) * 16;
        *(uint4*)(Wp4 + wo) = make_uint4(wd[0], wd[1], wd[2], wd[3]);
        scl[(((size_t)bl * 4 + mat) * 2 + gp) * 1024 + (size_t)lane * 16 + kt] = (uchar)(ee + 127);
    }
}

__global__ void k_bias(const float* __restrict__ bi0, const float* __restrict__ bh0,
                       const float* __restrict__ bi1, const float* __restrict__ bh1,
                       float* __restrict__ bias0, float* __restrict__ bias1) {
    int i = blockIdx.x * blockDim.x + threadIdx.x;
    if (i < 4 * FDIM) {
        bias0[i] = bi0[i] + bh0[i];
        bias1[i] = bi1[i] + bh1[i];
    }
}

// ---------------- input 1x1 conv -> seq slots in MFMA-FRAGMENT layout, fp8 (x4) ----------------
// slot layout: [kt(16)][lane(64)][32B], k = kt*128 + (lane>>4)*32 + byte, row b = lane&15
__global__ __launch_bounds__(256) void k_seqprep(const float* __restrict__ x,
                                                 const float* __restrict__ w_in,
                                                 const float* __restrict__ b_in,
                                                 uchar* __restrict__ seqb) {
    int h = blockIdx.x >> 4, b = blockIdx.x & 15;
    __shared__ float xs[256][32];
    __shared__ float wl[64][257];
    int tid = threadIdx.x;
    for (int i = tid; i < 256 * 32; i += 256) {
        int c = i >> 5, w = i & 31;
        xs[c][w] = x[(((size_t)b * 256 + c) * 32 + h) * 32 + w];
    }
    for (int i = tid; i < 64 * 256; i += 256) {
        int cb = i >> 8, c = i & 255;
        wl[cb][c] = w_in[i];
    }
    __syncthreads();
    int w = (tid * 8) >> 6, cb0 = (tid * 8) & 63;
    float acc[8];
#pragma unroll
    for (int j = 0; j < 8; ++j) acc[j] = b_in[cb0 + j];
    for (int c = 0; c < 256; ++c) {
        float xv = xs[c][w];
#pragma unroll
        for (int j = 0; j < 8; ++j) acc[j] += xv * wl[cb0 + j][c];
    }
    unsigned lo = 0, hi2 = 0;
#pragma unroll
    for (int j = 0; j < 4; ++j) lo |= f2fp8(acc[j] * 4.0f) << (j * 8);
#pragma unroll
    for (int j = 0; j < 4; ++j) hi2 |= f2fp8(acc[4 + j] * 4.0f) << (j * 8);
    int kt = tid >> 4, kq = (tid >> 2) & 3, e0 = (tid & 3) * 8;
    uchar* dst = seqb + (size_t)h * 32768 + (size_t)kt * 2048 + (size_t)(b + 16 * kq) * 32 + e0;
    *(uint2*)dst = make_uint2(lo, hi2);
}

// ---------------- persistent LSTM: LDS-resident fp4 weights, fragment-layout activations -------
// 9 waves (576 thr): w<8 compute (gp = w&1, m = (w>>1)&1, kh = w>>2); w==8 dedicated poller.
// wave 8: polls 256 plain-store tags (32B apart) for row c-1 -> LDS flag release.
// wave 7: producer tail (gate update, h publish, wave-local drain, 1 plain tag store).
__global__ __launch_bounds__(576, 1) void k_lstm(const uchar* __restrict__ Wp4,
                                                 const uchar* __restrict__ scl,
                                                 const float* __restrict__ bias0,
                                                 const float* __restrict__ bias1,
                                                 const uchar* __restrict__ seqb,
                                                 uchar* __restrict__ H0, uchar* __restrict__ H1,
                                                 u16* __restrict__ seqout,
                                                 unsigned* __restrict__ tags) {
    __shared__ uchar wlds[131072];            // [mat*2+gp][kt][lane*16]
    __shared__ float gbuf[2][8][16][20];      // cell-parity dbuf; col pad 16->20 (bank fix)
    __shared__ u64 hs_st[16];
    __shared__ unsigned flagLDS;
    const int tid = threadIdx.x, lane = tid & 63, w = tid >> 6;
    const int gp = w & 1, m = (w >> 1) & 1, kh = w >> 2;
    const int bl = blockIdx.x;
    const size_t BF = (size_t)16 * FDIM;

    {
        const uchar* src = Wp4 + (size_t)bl * 131072;
        for (int i = tid; i < 8192; i += 576)
            *(uint4*)(wlds + (size_t)i * 16) = *(const uint4*)(src + (size_t)i * 16);
    }
    uint4 scl0, scl1;
    if (w < 8) {
        scl0 = *(const uint4*)(scl + (((size_t)bl * 4 + m) * 2 + gp) * 1024 + (size_t)lane * 16);
        scl1 = *(const uint4*)(scl + (((size_t)bl * 4 + 2 + m) * 2 + gp) * 1024 + (size_t)lane * 16);
    }

    // wave-7 tail state: per-lane 2 (b,f) pairs; b = lane>>2, f = (lane&3)*2 + i
    float bw0[2][4], bw1[2][4];
    float cs0[2] = {0.f, 0.f}, cs1[2] = {0.f, 0.f};
    if (w == 7) {
        const int f0 = (lane & 3) * 2;
#pragma unroll
        for (int i = 0; i < 2; ++i) {
            int col = bl * 8 + f0 + i;
#pragma unroll
            for (int g = 0; g < 4; ++g) {
                bw0[i][g] = bias0[g * FDIM + col];
                bw1[i][g] = bias1[g * FDIM + col];
            }
        }
    }
    if (tid == 0) flagLDS = 0;
    __syncthreads();

    const int b16 = lane & 15, kq = lane >> 4;
    for (int c = 0; c < NCELL; ++c) {
        const int s = c >> 1, isL1 = c & 1, par = c & 1;
        const uchar* xsrc = isL1 ? (H0 + (size_t)(s + 1) * BF)
                          : (s < 32 ? (seqb + (size_t)s * BF) : (H1 + (size_t)s * BF));
        const uchar* hsrc = isL1 ? (H1 + (size_t)s * BF) : (H0 + (size_t)s * BF);
        const bool staticX = (!isL1 && s < 32);

        if (w == 8) {
            // dedicated poller: verify tag row c-1 (all 256 blocks), then release via LDS flag
            if (c >= 1) {
                const unsigned* trow = tags + (size_t)(c - 1) * 2048;
                for (;;) {
                    unsigned v0 = __hip_atomic_load(trow + (size_t)lane * 8,
                                                    __ATOMIC_RELAXED, __HIP_MEMORY_SCOPE_AGENT);
                    unsigned v1 = __hip_atomic_load(trow + (size_t)(lane + 64) * 8,
                                                    __ATOMIC_RELAXED, __HIP_MEMORY_SCOPE_AGENT);
                    unsigned v2 = __hip_atomic_load(trow + (size_t)(lane + 128) * 8,
                                                    __ATOMIC_RELAXED, __HIP_MEMORY_SCOPE_AGENT);
                    unsigned v3 = __hip_atomic_load(trow + (size_t)(lane + 192) * 8,
                                                    __ATOMIC_RELAXED, __HIP_MEMORY_SCOPE_AGENT);
                    if ((v0 & v1 & v2 & v3) == 1u) break;
                    __builtin_amdgcn_s_sleep(1);
                }
                if (lane == 0)
                    __hip_atomic_store(&flagLDS, (unsigned)c,
                                       __ATOMIC_RELAXED, __HIP_MEMORY_SCOPE_WORKGROUP);
            }
        } else {
            const uchar* asrc = m ? hsrc : xsrc;
            // dependency: ih fresh (flag>=c, unless static input), hh 2 cells old (flag>=c-1)
            unsigned need = m ? ((c >= 2) ? (unsigned)(c - 1) : 0u)
                             : (staticX ? 0u : (unsigned)c);
            if (need)
                while (__hip_atomic_load(&flagLDS, __ATOMIC_RELAXED,
                                         __HIP_MEMORY_SCOPE_WORKGROUP) < need)
                    __builtin_amdgcn_s_sleep(1);
            asm volatile("" ::: "memory");

            // fragment-layout A loads, block-staggered issue order (slots unchanged)
            const uchar* ap = asrc + (size_t)lane * 32;
            uint4 A[8][2];
#pragma unroll
            for (int t = 0; t < 8; ++t) {
                int tt = (t + bl) & 7;
                A[tt][0] = *(const uint4*)(ap + (size_t)(kh * 8 + tt) * 2048);
                A[tt][1] = *(const uint4*)(ap + (size_t)(kh * 8 + tt) * 2048 + 16);
            }
            const uchar* bp = wlds + (size_t)((isL1 * 2 + m) * 2 + gp) * 16384 + lane * 16;
            uint4 sv = isL1 ? scl1 : scl0;
            unsigned sw0 = kh ? sv.z : sv.x;
            unsigned sw1 = kh ? sv.w : sv.y;

            f32x4 acc0 = {0.f, 0.f, 0.f, 0.f}, acc1 = {0.f, 0.f, 0.f, 0.f};
#define MF(T, SW, J)                                                                   \
            {                                                                          \
                uint4 alo = A[T][0], ahi = A[T][1];                                    \
                uint4 bb = *(const uint4*)(bp + (kh * 8 + (T)) * 1024);                \
                i8v av = {(int)alo.x, (int)alo.y, (int)alo.z, (int)alo.w,              \
                          (int)ahi.x, (int)ahi.y, (int)ahi.z, (int)ahi.w};             \
                i8v bv = {(int)bb.x, (int)bb.y, (int)bb.z, (int)bb.w, 0, 0, 0, 0};     \
                if ((T) & 1)                                                           \
                    acc1 = __builtin_amdgcn_mfma_scale_f32_16x16x128_f8f6f4(           \
                        av, bv, acc1, 0, 4, 0, 127, J, (int)(SW));                     \
                else                                                                   \
                    acc0 = __builtin_amdgcn_mfma_scale_f32_16x16x128_f8f6f4(           \
                        av, bv, acc0, 0, 4, 0, 127, J, (int)(SW));                     \
            }
            MF(0, sw0, 0); MF(1, sw0, 1); MF(2, sw0, 2); MF(3, sw0, 3);
            MF(4, sw1, 0); MF(5, sw1, 1); MF(6, sw1, 2); MF(7, sw1, 3);
#undef MF
            f32x4 acc = acc0 + acc1;
#pragma unroll
            for (int i = 0; i < 4; ++i) gbuf[par][w][kq * 4 + i][b16] = acc[i];
        }
        __syncthreads();   // S1 — the only block-wide barrier per cell

        if (w == 7) {
            // gate update for 2 (b,f) pairs per lane
            const int b = lane >> 2, f0 = (lane & 3) * 2;
            u16 hb2 = 0;
            float hnv[2];
#pragma unroll
            for (int i = 0; i < 2; ++i) {
                const int f = f0 + i;
                float gv[4];
#pragma unroll
                for (int g = 0; g < 4; ++g) {
                    int gpp = g >> 1, jl = ((g & 1) << 3) | f;
                    gv[g] = (gbuf[par][gpp][b][jl] + gbuf[par][gpp + 2][b][jl]
                           + gbuf[par][gpp + 4][b][jl] + gbuf[par][gpp + 6][b][jl]) * 0.25f
                           + (isL1 ? bw1[i][g] : bw0[i][g]);
                }
                float co = isL1 ? cs1[i] : cs0[i];
                float cn = sigm(gv[1]) * co + sigm(gv[0]) * tanh_f(gv[2]);
                float hn = sigm(gv[3]) * tanh_f(cn);
                if (isL1) cs1[i] = cn; else cs0[i] = cn;
                hb2 |= (u16)(f2fp8(hn * 4.0f) << (8 * i));
                hnv[i] = hn;
            }
            *(u16*)((uchar*)&hs_st[b] + f0) = hb2;
            asm volatile("s_waitcnt lgkmcnt(0)" ::: "memory");
            if (lane < 16) {
                // fragment-layout publish: features bl*8..bl*8+7
                uchar* hdst = (isL1 ? H1 : H0) + (size_t)(s + 1) * BF;
                size_t o = (size_t)(bl >> 4) * 2048 + (size_t)((bl >> 2) & 3) * 512
                         + (size_t)(bl & 3) * 8 + (size_t)lane * 32;
                __hip_atomic_store((u64*)(hdst + o), hs_st[lane],
                                   __ATOMIC_RELAXED, __HIP_MEMORY_SCOPE_AGENT);
            }
            asm volatile("s_waitcnt vmcnt(0)" ::: "memory");   // h acked at L3
            if (lane == 0)
                __hip_atomic_store(tags + (size_t)c * 2048 + (size_t)bl * 8, 1u,
                                   __ATOMIC_RELAXED, __HIP_MEMORY_SCOPE_AGENT);
            if (isL1 && s >= 31) {   // off the notify path (row-major bf16 for convout)
                unsigned pk = (unsigned)f2b(hnv[0]) | ((unsigned)f2b(hnv[1]) << 16);
                *(unsigned*)(seqout + (size_t)(s - 31) * BF + (size_t)b * FDIM + bl * 8 + f0) = pk;
            }
        }
    }
}

// ---------------- copy x into top half of output ----------------
__global__ void k_copyx(const float* __restrict__ x, float* __restrict__ out) {
    size_t n = (size_t)4096 * 256;
    size_t stride = (size_t)gridDim.x * blockDim.x;
    for (size_t i = (size_t)blockIdx.x * blockDim.x + threadIdx.x; i < n; i += stride) {
        size_t bc = i >> 8, r = i & 255;
        ((float4*)out)[bc * 512 + r] = ((const float4*)x)[i];
    }
}

// ---------------- output 1x1 conv into bottom half ----------------
__global__ __launch_bounds__(256) void k_convout(const u16* __restrict__ seqout,
                                                 const float* __restrict__ w_out,
                                                 const float* __restrict__ b_out,
                                                 float* __restrict__ out) {
    int s = blockIdx.x >> 4, b = blockIdx.x & 15;
    __shared__ float srow[2048];
    int tid = threadIdx.x;
    for (int i = tid; i < 2048; i += 256) srow[i] = b2f(seqout[((size_t)s * 16 + b) * FDIM + i]);
    __syncthreads();
    int o = tid;
    float bo = b_out[o];
    float wreg[64];
#pragma unroll
    for (int cb = 0; cb < 64; ++cb) wreg[cb] = w_out[o * 64 + cb];
    for (int w4 = 0; w4 < 8; ++w4) {
        float ac0 = bo, ac1 = bo, ac2 = bo, ac3 = bo;
#pragma unroll
        for (int cb = 0; cb < 64; ++cb) {
            float wv = wreg[cb];
            ac0 += srow[(w4 * 4 + 0) * 64 + cb] * wv;
            ac1 += srow[(w4 * 4 + 1) * 64 + cb] * wv;
            ac2 += srow[(w4 * 4 + 2) * 64 + cb] * wv;
            ac3 += srow[(w4 * 4 + 3) * 64 + cb] * wv;
        }
        float4 v; v.x = ac0; v.y = ac1; v.z = ac2; v.w = ac3;
        *(float4*)&out[(((size_t)b * 256 + o) * 64 + 32 + s) * 32 + w4 * 4] = v;
    }
}

extern "C" void kernel_launch(void* const* d_in, const int* in_sizes, int n_in,
                              void* d_out, int out_size, void* d_ws, size_t ws_size,
                              hipStream_t stream) {
    const float* x    = (const float*)d_in[0];
    const float* w_in = (const float*)d_in[1];
    const float* b_in = (const float*)d_in[2];
    const float* Wih0 = (const float*)d_in[3];
    const float* Whh0 = (const float*)d_in[4];
    const float* bih0 = (const float*)d_in[5];
    const float* bhh0 = (const float*)d_in[6];
    const float* Wih1 = (const float*)d_in[7];
    const float* Whh1 = (const float*)d_in[8];
    const float* bih1 = (const float*)d_in[9];
    const float* bhh1 = (const float*)d_in[10];
    const float* wout = (const float*)d_in[11];
    const float* bout = (const float*)d_in[12];
    float* out = (float*)d_out;
    char* ws = (char*)d_ws;
    const size_t BF = (size_t)16 * FDIM;

    uchar* Wp4 = (uchar*)ws;
    size_t off = (size_t)NBLK * 131072;                       // 32 MiB packed fp4 weights
    uchar* scl = (uchar*)(ws + off); off += (size_t)NBLK * 4 * 2 * 1024;   // 2 MiB scales
    float* bias0 = (float*)(ws + off); off += 4 * FDIM * 4;
    float* bias1 = (float*)(ws + off); off += 4 * FDIM * 4;
    uchar* seqb = (uchar*)(ws + off); off += (size_t)32 * BF;              // 1 MiB
    u16* seqout = (u16*)(ws + off); off += (size_t)32 * BF * 2;            // 2 MiB
    uchar* H0 = (uchar*)(ws + off); off += (size_t)64 * BF;                // 2 MiB (rotating slots)
    uchar* H1 = (uchar*)(ws + off); off += (size_t)64 * BF;                // 2 MiB
    off = (off + 127) & ~(size_t)127;
    unsigned* tags = (unsigned*)(ws + off); size_t tagoff = off;
    off += (size_t)NCELL * 2048 * 4;                          // 126 rows x 256 tags x 32B

    // zero: H0 slot0, H1 slot0, tag rows (in-graph, every replay)
    hipMemsetAsync(H0, 0, BF, stream);
    hipMemsetAsync(H1, 0, BF, stream);
    hipMemsetAsync(ws + tagoff, 0, off - tagoff, stream);

    k_pack4<<<256 * 4 * 16, 256, 0, stream>>>(Wih0, Whh0, Wih1, Whh1, Wp4, scl);
    k_bias<<<32, 256, 0, stream>>>(bih0, bhh0, bih1, bhh1, bias0, bias1);
    k_seqprep<<<512, 256, 0, stream>>>(x, w_in, b_in, seqb);
    k_lstm<<<NBLK, 576, 0, stream>>>(Wp4, scl, bias0, bias1, seqb, H0, H1, seqout, tags);
    k_copyx<<<2048, 256, 0, stream>>>(x, out);
    k_convout<<<512, 256, 0, stream>>>(seqout, wout, bout, out);
}

// Round 11
// 651.690 us; speedup vs baseline: 2.3902x; 2.3902x over previous
//
#include <hip/hip_runtime.h>
#include <hip/hip_bf16.h>

typedef unsigned short u16;
typedef unsigned char uchar;
typedef unsigned long long u64;
typedef float f32x4 __attribute__((ext_vector_type(4)));
typedef int i8v __attribute__((ext_vector_type(8)));

#define FDIM 2048
#define NBLK 256
#define NCELL 126

__device__ __forceinline__ u16 f2b(float x) {
    __hip_bfloat16 h = __float2bfloat16(x);
    return __builtin_bit_cast(u16, h);
}
__device__ __forceinline__ float b2f(u16 u) {
    __hip_bfloat16 h = __builtin_bit_cast(__hip_bfloat16, u);
    return __bfloat162float(h);
}
__device__ __forceinline__ float sigm(float x) { return 1.0f / (1.0f + __expf(-x)); }
__device__ __forceinline__ float tanh_f(float x) { return 1.0f - 2.0f / (__expf(2.0f * x) + 1.0f); }

// OCP e4m3 encode (RNE), saturate to 448.
__device__ __forceinline__ unsigned f2fp8(float x) {
    unsigned u = __builtin_bit_cast(unsigned, x);
    unsigned s = (u >> 24) & 0x80u;
    unsigned mag = u & 0x7fffffffu;
    if (mag >= 0x43E80000u) return s | 0x7Eu;
    int e = (int)(mag >> 23) - 127;
    if (e >= -6) {
        unsigned m = mag + 0x7FFFFu + ((mag >> 20) & 1u);
        unsigned e8 = (m >> 23) - 127 + 7;
        unsigned m3 = (m >> 20) & 7u;
        if (e8 >= 16u) return s | 0x7Eu;
        return s | (e8 << 3) | m3;
    }
    float ax = __builtin_bit_cast(float, mag);
    int d = (int)__builtin_rintf(ax * 512.0f);
    return s | (unsigned)d;
}

// e2m1 (fp4) quantize of v (|v|<=6 after scaling): returns 4-bit code
__device__ __forceinline__ unsigned q_e2m1(float v) {
    unsigned s = (v < 0.f) ? 8u : 0u;
    float a = fabsf(v);
    unsigned q;
    if (a < 0.25f) q = 0;
    else if (a < 0.75f) q = 1;
    else if (a < 1.25f) q = 2;
    else if (a < 1.75f) q = 3;
    else if (a < 2.5f)  q = 4;
    else if (a < 3.5f)  q = 5;
    else if (a < 5.0f)  q = 6;
    else q = 7;
    return s | q;
}

// ---------------- weight pack: fp32 -> MX fp4 (E8M0 per-32 scales), MFMA fragment order ----------
__global__ __launch_bounds__(256) void k_pack4(const float* __restrict__ W0, const float* __restrict__ W1,
                                               const float* __restrict__ W2, const float* __restrict__ W3,
                                               uchar* __restrict__ Wp4, uchar* __restrict__ scl) {
    __shared__ float lw[32][132];
    int idx = blockIdx.x;                 // [0, 256*4*16)
    int kt = idx & 15, mat = (idx >> 4) & 3, bl = idx >> 6;
    const float* src = mat == 0 ? W0 : mat == 1 ? W1 : mat == 2 ? W2 : W3;
    int tid = threadIdx.x;
    for (int i = tid; i < 32 * 32; i += 256) {
        int r = i >> 5, c4 = i & 31;
        const float* p = src + (size_t)((r >> 3) * 2048 + bl * 8 + (r & 7)) * 2048 + kt * 128 + c4 * 4;
        float4 v = *(const float4*)p;
        lw[r][c4 * 4 + 0] = v.x; lw[r][c4 * 4 + 1] = v.y;
        lw[r][c4 * 4 + 2] = v.z; lw[r][c4 * 4 + 3] = v.w;
    }
    __syncthreads();
    if (tid < 128) {
        int gp = tid >> 6, lane = tid & 63;
        int r = (2 * gp + ((lane & 15) >> 3)) * 8 + (lane & 7);
        int k0 = (lane >> 4) * 32;
        float mx = 0.f;
#pragma unroll
        for (int e = 0; e < 32; ++e) mx = fmaxf(mx, fabsf(lw[r][k0 + e]));
        int ee = -127;
        if (mx > 0.f) {
            ee = (int)ceilf(log2f(mx * (1.0f / 6.0f)));
            if (ee < -127) ee = -127;
            if (ee > 127) ee = 127;
        }
        float inv = exp2f((float)(-ee));
        unsigned wd[4];
#pragma unroll
        for (int d = 0; d < 4; ++d) {
            unsigned acc = 0;
#pragma unroll
            for (int bi = 0; bi < 4; ++bi) {
                float v0 = lw[r][k0 + d * 8 + 2 * bi] * inv;
                float v1 = lw[r][k0 + d * 8 + 2 * bi + 1] * inv;
                acc |= (q_e2m1(v0) << (bi * 8)) | (q_e2m1(v1) << (bi * 8 + 4));
            }
            wd[d] = acc;
        }
        size_t wo = (size_t)bl * 131072 + (((size_t)(mat * 2 + gp) * 16 + (size_t)kt) * 64 + lane) * 16;
        *(uint4*)(Wp4 + wo) = make_uint4(wd[0], wd[1], wd[2], wd[3]);
        scl[(((size_t)bl * 4 + mat) * 2 + gp) * 1024 + (size_t)lane * 16 + kt] = (uchar)(ee + 127);
    }
}

__global__ void k_bias(const float* __restrict__ bi0, const float* __restrict__ bh0,
                       const float* __restrict__ bi1, const float* __restrict__ bh1,
                       float* __restrict__ bias0, float* __restrict__ bias1) {
    int i = blockIdx.x * blockDim.x + threadIdx.x;
    if (i < 4 * FDIM) {
        bias0[i] = bi0[i] + bh0[i];
        bias1[i] = bi1[i] + bh1[i];
    }
}

// ---------------- input 1x1 conv -> seq slots in MFMA-FRAGMENT layout, fp8 (x4) ----------------
// slot layout: [kt(16)][lane(64)][32B], k = kt*128 + (lane>>4)*32 + byte, row b = lane&15
__global__ __launch_bounds__(256) void k_seqprep(const float* __restrict__ x,
                                                 const float* __restrict__ w_in,
                                                 const float* __restrict__ b_in,
                                                 uchar* __restrict__ seqb) {
    int h = blockIdx.x >> 4, b = blockIdx.x & 15;
    __shared__ float xs[256][32];
    __shared__ float wl[64][257];
    int tid = threadIdx.x;
    for (int i = tid; i < 256 * 32; i += 256) {
        int c = i >> 5, w = i & 31;
        xs[c][w] = x[(((size_t)b * 256 + c) * 32 + h) * 32 + w];
    }
    for (int i = tid; i < 64 * 256; i += 256) {
        int cb = i >> 8, c = i & 255;
        wl[cb][c] = w_in[i];
    }
    __syncthreads();
    int w = (tid * 8) >> 6, cb0 = (tid * 8) & 63;
    float acc[8];
#pragma unroll
    for (int j = 0; j < 8; ++j) acc[j] = b_in[cb0 + j];
    for (int c = 0; c < 256; ++c) {
        float xv = xs[c][w];
#pragma unroll
        for (int j = 0; j < 8; ++j) acc[j] += xv * wl[cb0 + j][c];
    }
    unsigned lo = 0, hi2 = 0;
#pragma unroll
    for (int j = 0; j < 4; ++j) lo |= f2fp8(acc[j] * 4.0f) << (j * 8);
#pragma unroll
    for (int j = 0; j < 4; ++j) hi2 |= f2fp8(acc[4 + j] * 4.0f) << (j * 8);
    int kt = tid >> 4, kq = (tid >> 2) & 3, e0 = (tid & 3) * 8;
    uchar* dst = seqb + (size_t)h * 32768 + (size_t)kt * 2048 + (size_t)(b + 16 * kq) * 32 + e0;
    *(uint2*)dst = make_uint2(lo, hi2);
}

// ---------------- persistent LSTM: LDS-resident fp4 weights, fragment-layout activations -------
// 9 waves (576 thr): w<8 compute (gp = w&1, m = (w>>1)&1, kh = w>>2); w==8 dedicated poller.
// wave 8: polls 256 plain-store tags (32B apart) for row c-1 -> LDS flag release.
// wave 7: producer tail (gate update, h publish, wave-local drain, 1 plain tag store).
// NOTE: all register-array indices are compile-time constants (rule #20: no scratch).
__global__ __launch_bounds__(576, 1) void k_lstm(const uchar* __restrict__ Wp4,
                                                 const uchar* __restrict__ scl,
                                                 const float* __restrict__ bias0,
                                                 const float* __restrict__ bias1,
                                                 const uchar* __restrict__ seqb,
                                                 uchar* __restrict__ H0, uchar* __restrict__ H1,
                                                 u16* __restrict__ seqout,
                                                 unsigned* __restrict__ tags) {
    __shared__ uchar wlds[131072];            // [mat*2+gp][kt][lane*16]
    __shared__ float gbuf[2][8][16][20];      // cell-parity dbuf; col pad 16->20 (bank fix)
    __shared__ u64 hs_st[16];
    __shared__ unsigned flagLDS;
    const int tid = threadIdx.x, lane = tid & 63, w = tid >> 6;
    const int gp = w & 1, m = (w >> 1) & 1, kh = w >> 2;
    const int bl = blockIdx.x;
    const size_t BF = (size_t)16 * FDIM;

    {
        const uchar* src = Wp4 + (size_t)bl * 131072;
        for (int i = tid; i < 8192; i += 576)
            *(uint4*)(wlds + (size_t)i * 16) = *(const uint4*)(src + (size_t)i * 16);
    }
    uint4 scl0, scl1;
    if (w < 8) {
        scl0 = *(const uint4*)(scl + (((size_t)bl * 4 + m) * 2 + gp) * 1024 + (size_t)lane * 16);
        scl1 = *(const uint4*)(scl + (((size_t)bl * 4 + 2 + m) * 2 + gp) * 1024 + (size_t)lane * 16);
    }

    // wave-7 tail state: per-lane 2 (b,f) pairs; b = lane>>2, f = (lane&3)*2 + i
    float bw0[2][4], bw1[2][4];
    float cs0[2] = {0.f, 0.f}, cs1[2] = {0.f, 0.f};
    if (w == 7) {
        const int f0 = (lane & 3) * 2;
#pragma unroll
        for (int i = 0; i < 2; ++i) {
            int col = bl * 8 + f0 + i;
#pragma unroll
            for (int g = 0; g < 4; ++g) {
                bw0[i][g] = bias0[g * FDIM + col];
                bw1[i][g] = bias1[g * FDIM + col];
            }
        }
    }
    if (tid == 0) flagLDS = 0;
    __syncthreads();

    const int b16 = lane & 15, kq = lane >> 4;
    for (int c = 0; c < NCELL; ++c) {
        const int s = c >> 1, isL1 = c & 1, par = c & 1;
        const uchar* xsrc = isL1 ? (H0 + (size_t)(s + 1) * BF)
                          : (s < 32 ? (seqb + (size_t)s * BF) : (H1 + (size_t)s * BF));
        const uchar* hsrc = isL1 ? (H1 + (size_t)s * BF) : (H0 + (size_t)s * BF);
        const bool staticX = (!isL1 && s < 32);

        if (w == 8) {
            // dedicated poller: verify tag row c-1 (all 256 blocks), then release via LDS flag
            if (c >= 1) {
                const unsigned* trow = tags + (size_t)(c - 1) * 2048;
                for (;;) {
                    unsigned v0 = __hip_atomic_load(trow + (size_t)lane * 8,
                                                    __ATOMIC_RELAXED, __HIP_MEMORY_SCOPE_AGENT);
                    unsigned v1 = __hip_atomic_load(trow + (size_t)(lane + 64) * 8,
                                                    __ATOMIC_RELAXED, __HIP_MEMORY_SCOPE_AGENT);
                    unsigned v2 = __hip_atomic_load(trow + (size_t)(lane + 128) * 8,
                                                    __ATOMIC_RELAXED, __HIP_MEMORY_SCOPE_AGENT);
                    unsigned v3 = __hip_atomic_load(trow + (size_t)(lane + 192) * 8,
                                                    __ATOMIC_RELAXED, __HIP_MEMORY_SCOPE_AGENT);
                    if ((v0 & v1 & v2 & v3) == 1u) break;
                    __builtin_amdgcn_s_sleep(1);
                }
                if (lane == 0)
                    __hip_atomic_store(&flagLDS, (unsigned)c,
                                       __ATOMIC_RELAXED, __HIP_MEMORY_SCOPE_WORKGROUP);
            }
        } else {
            const uchar* asrc = m ? hsrc : xsrc;
            // dependency: ih fresh (flag>=c, unless static input), hh 2 cells old (flag>=c-1)
            unsigned need = m ? ((c >= 2) ? (unsigned)(c - 1) : 0u)
                             : (staticX ? 0u : (unsigned)c);
            if (need)
                while (__hip_atomic_load(&flagLDS, __ATOMIC_RELAXED,
                                         __HIP_MEMORY_SCOPE_WORKGROUP) < need)
                    __builtin_amdgcn_s_sleep(1);
            asm volatile("" ::: "memory");

            // fragment-layout A loads: static issue order, compile-time indices only
            const uchar* ap = asrc + (size_t)lane * 32;
            uint4 A[8][2];
#pragma unroll
            for (int t = 0; t < 8; ++t) {
                A[t][0] = *(const uint4*)(ap + (size_t)(kh * 8 + t) * 2048);
                A[t][1] = *(const uint4*)(ap + (size_t)(kh * 8 + t) * 2048 + 16);
            }
            const uchar* bp = wlds + (size_t)((isL1 * 2 + m) * 2 + gp) * 16384 + lane * 16;
            uint4 sv = isL1 ? scl1 : scl0;
            unsigned sw0 = kh ? sv.z : sv.x;
            unsigned sw1 = kh ? sv.w : sv.y;

            f32x4 acc0 = {0.f, 0.f, 0.f, 0.f}, acc1 = {0.f, 0.f, 0.f, 0.f};
#define MF(T, SW, J)                                                                   \
            {                                                                          \
                uint4 alo = A[T][0], ahi = A[T][1];                                    \
                uint4 bb = *(const uint4*)(bp + (kh * 8 + (T)) * 1024);                \
                i8v av = {(int)alo.x, (int)alo.y, (int)alo.z, (int)alo.w,              \
                          (int)ahi.x, (int)ahi.y, (int)ahi.z, (int)ahi.w};             \
                i8v bv = {(int)bb.x, (int)bb.y, (int)bb.z, (int)bb.w, 0, 0, 0, 0};     \
                if ((T) & 1)                                                           \
                    acc1 = __builtin_amdgcn_mfma_scale_f32_16x16x128_f8f6f4(           \
                        av, bv, acc1, 0, 4, 0, 127, J, (int)(SW));                     \
                else                                                                   \
                    acc0 = __builtin_amdgcn_mfma_scale_f32_16x16x128_f8f6f4(           \
                        av, bv, acc0, 0, 4, 0, 127, J, (int)(SW));                     \
            }
            MF(0, sw0, 0); MF(1, sw0, 1); MF(2, sw0, 2); MF(3, sw0, 3);
            MF(4, sw1, 0); MF(5, sw1, 1); MF(6, sw1, 2); MF(7, sw1, 3);
#undef MF
            f32x4 acc = acc0 + acc1;
#pragma unroll
            for (int i = 0; i < 4; ++i) gbuf[par][w][kq * 4 + i][b16] = acc[i];
        }
        __syncthreads();   // S1 — the only block-wide barrier per cell

        if (w == 7) {
            // gate update for 2 (b,f) pairs per lane
            const int b = lane >> 2, f0 = (lane & 3) * 2;
            u16 hb2 = 0;
            float hnv[2];
#pragma unroll
            for (int i = 0; i < 2; ++i) {
                const int f = f0 + i;
                float gv[4];
#pragma unroll
                for (int g = 0; g < 4; ++g) {
                    int gpp = g >> 1, jl = ((g & 1) << 3) | f;
                    gv[g] = (gbuf[par][gpp][b][jl] + gbuf[par][gpp + 2][b][jl]
                           + gbuf[par][gpp + 4][b][jl] + gbuf[par][gpp + 6][b][jl]) * 0.25f
                           + (isL1 ? bw1[i][g] : bw0[i][g]);
                }
                float co = isL1 ? cs1[i] : cs0[i];
                float cn = sigm(gv[1]) * co + sigm(gv[0]) * tanh_f(gv[2]);
                float hn = sigm(gv[3]) * tanh_f(cn);
                if (isL1) cs1[i] = cn; else cs0[i] = cn;
                hb2 |= (u16)(f2fp8(hn * 4.0f) << (8 * i));
                hnv[i] = hn;
            }
            *(u16*)((uchar*)&hs_st[b] + f0) = hb2;
            asm volatile("s_waitcnt lgkmcnt(0)" ::: "memory");
            if (lane < 16) {
                // fragment-layout publish: features bl*8..bl*8+7
                uchar* hdst = (isL1 ? H1 : H0) + (size_t)(s + 1) * BF;
                size_t o = (size_t)(bl >> 4) * 2048 + (size_t)((bl >> 2) & 3) * 512
                         + (size_t)(bl & 3) * 8 + (size_t)lane * 32;
                __hip_atomic_store((u64*)(hdst + o), hs_st[lane],
                                   __ATOMIC_RELAXED, __HIP_MEMORY_SCOPE_AGENT);
            }
            asm volatile("s_waitcnt vmcnt(0)" ::: "memory");   // h acked at L3
            if (lane == 0)
                __hip_atomic_store(tags + (size_t)c * 2048 + (size_t)bl * 8, 1u,
                                   __ATOMIC_RELAXED, __HIP_MEMORY_SCOPE_AGENT);
            if (isL1 && s >= 31) {   // off the notify path (row-major bf16 for convout)
                unsigned pk = (unsigned)f2b(hnv[0]) | ((unsigned)f2b(hnv[1]) << 16);
                *(unsigned*)(seqout + (size_t)(s - 31) * BF + (size_t)b * FDIM + bl * 8 + f0) = pk;
            }
        }
    }
}

// ---------------- copy x into top half of output ----------------
__global__ void k_copyx(const float* __restrict__ x, float* __restrict__ out) {
    size_t n = (size_t)4096 * 256;
    size_t stride = (size_t)gridDim.x * blockDim.x;
    for (size_t i = (size_t)blockIdx.x * blockDim.x + threadIdx.x; i < n; i += stride) {
        size_t bc = i >> 8, r = i & 255;
        ((float4*)out)[bc * 512 + r] = ((const float4*)x)[i];
    }
}

// ---------------- output 1x1 conv into bottom half ----------------
__global__ __launch_bounds__(256) void k_convout(const u16* __restrict__ seqout,
                                                 const float* __restrict__ w_out,
                                                 const float* __restrict__ b_out,
                                                 float* __restrict__ out) {
    int s = blockIdx.x >> 4, b = blockIdx.x & 15;
    __shared__ float srow[2048];
    int tid = threadIdx.x;
    for (int i = tid; i < 2048; i += 256) srow[i] = b2f(seqout[((size_t)s * 16 + b) * FDIM + i]);
    __syncthreads();
    int o = tid;
    float bo = b_out[o];
    float wreg[64];
#pragma unroll
    for (int cb = 0; cb < 64; ++cb) wreg[cb] = w_out[o * 64 + cb];
    for (int w4 = 0; w4 < 8; ++w4) {
        float ac0 = bo, ac1 = bo, ac2 = bo, ac3 = bo;
#pragma unroll
        for (int cb = 0; cb < 64; ++cb) {
            float wv = wreg[cb];
            ac0 += srow[(w4 * 4 + 0) * 64 + cb] * wv;
            ac1 += srow[(w4 * 4 + 1) * 64 + cb] * wv;
            ac2 += srow[(w4 * 4 + 2) * 64 + cb] * wv;
            ac3 += srow[(w4 * 4 + 3) * 64 + cb] * wv;
        }
        float4 v; v.x = ac0; v.y = ac1; v.z = ac2; v.w = ac3;
        *(float4*)&out[(((size_t)b * 256 + o) * 64 + 32 + s) * 32 + w4 * 4] = v;
    }
}

extern "C" void kernel_launch(void* const* d_in, const int* in_sizes, int n_in,
                              void* d_out, int out_size, void* d_ws, size_t ws_size,
                              hipStream_t stream) {
    const float* x    = (const float*)d_in[0];
    const float* w_in = (const float*)d_in[1];
    const float* b_in = (const float*)d_in[2];
    const float* Wih0 = (const float*)d_in[3];
    const float* Whh0 = (const float*)d_in[4];
    const float* bih0 = (const float*)d_in[5];
    const float* bhh0 = (const float*)d_in[6];
    const float* Wih1 = (const float*)d_in[7];
    const float* Whh1 = (const float*)d_in[8];
    const float* bih1 = (const float*)d_in[9];
    const float* bhh1 = (const float*)d_in[10];
    const float* wout = (const float*)d_in[11];
    const float* bout = (const float*)d_in[12];
    float* out = (float*)d_out;
    char* ws = (char*)d_ws;
    const size_t BF = (size_t)16 * FDIM;

    uchar* Wp4 = (uchar*)ws;
    size_t off = (size_t)NBLK * 131072;                       // 32 MiB packed fp4 weights
    uchar* scl = (uchar*)(ws + off); off += (size_t)NBLK * 4 * 2 * 1024;   // 2 MiB scales
    float* bias0 = (float*)(ws + off); off += 4 * FDIM * 4;
    float* bias1 = (float*)(ws + off); off += 4 * FDIM * 4;
    uchar* seqb = (uchar*)(ws + off); off += (size_t)32 * BF;              // 1 MiB
    u16* seqout = (u16*)(ws + off); off += (size_t)32 * BF * 2;            // 2 MiB
    uchar* H0 = (uchar*)(ws + off); off += (size_t)64 * BF;                // 2 MiB (rotating slots)
    uchar* H1 = (uchar*)(ws + off); off += (size_t)64 * BF;                // 2 MiB
    off = (off + 127) & ~(size_t)127;
    unsigned* tags = (unsigned*)(ws + off); size_t tagoff = off;
    off += (size_t)NCELL * 2048 * 4;                          // 126 rows x 256 tags x 32B

    // zero: H0 slot0, H1 slot0, tag rows (in-graph, every replay)
    hipMemsetAsync(H0, 0, BF, stream);
    hipMemsetAsync(H1, 0, BF, stream);
    hipMemsetAsync(ws + tagoff, 0, off - tagoff, stream);

    k_pack4<<<256 * 4 * 16, 256, 0, stream>>>(Wih0, Whh0, Wih1, Whh1, Wp4, scl);
    k_bias<<<32, 256, 0, stream>>>(bih0, bhh0, bih1, bhh1, bias0, bias1);
    k_seqprep<<<512, 256, 0, stream>>>(x, w_in, b_in, seqb);
    k_lstm<<<NBLK, 576, 0, stream>>>(Wp4, scl, bias0, bias1, seqb, H0, H1, seqout, tags);
    k_copyx<<<2048, 256, 0, stream>>>(x, out);
    k_convout<<<512, 256, 0, stream>>>(seqout, wout, bout, out);
}

// Round 12
// 620.531 us; speedup vs baseline: 2.5102x; 1.0502x over previous
//
#include <hip/hip_runtime.h>
#include <hip/hip_bf16.h>

typedef unsigned short u16;
typedef unsigned char uchar;
typedef unsigned long long u64;
typedef float f32x4 __attribute__((ext_vector_type(4)));
typedef int i8v __attribute__((ext_vector_type(8)));

#define FDIM 2048
#define NBLK 256
#define NSTEP 63
#define SLOT 32768   // bytes per h slot (16 x 2048 fp8)

__device__ __forceinline__ u16 f2b(float x) {
    __hip_bfloat16 h = __float2bfloat16(x);
    return __builtin_bit_cast(u16, h);
}
__device__ __forceinline__ float b2f(u16 u) {
    __hip_bfloat16 h = __builtin_bit_cast(__hip_bfloat16, u);
    return __bfloat162float(h);
}
__device__ __forceinline__ float sigm(float x) { return 1.0f / (1.0f + __expf(-x)); }
__device__ __forceinline__ float tanh_f(float x) { return 1.0f - 2.0f / (__expf(2.0f * x) + 1.0f); }

// OCP e4m3 encode (RNE), saturate to 448.
__device__ __forceinline__ unsigned f2fp8(float x) {
    unsigned u = __builtin_bit_cast(unsigned, x);
    unsigned s = (u >> 24) & 0x80u;
    unsigned mag = u & 0x7fffffffu;
    if (mag >= 0x43E80000u) return s | 0x7Eu;
    int e = (int)(mag >> 23) - 127;
    if (e >= -6) {
        unsigned m = mag + 0x7FFFFu + ((mag >> 20) & 1u);
        unsigned e8 = (m >> 23) - 127 + 7;
        unsigned m3 = (m >> 20) & 7u;
        if (e8 >= 16u) return s | 0x7Eu;
        return s | (e8 << 3) | m3;
    }
    float ax = __builtin_bit_cast(float, mag);
    int d = (int)__builtin_rintf(ax * 512.0f);
    return s | (unsigned)d;
}

// e2m1 (fp4) quantize (|v|<=6 after scaling)
__device__ __forceinline__ unsigned q_e2m1(float v) {
    unsigned s = (v < 0.f) ? 8u : 0u;
    float a = fabsf(v);
    unsigned q;
    if (a < 0.25f) q = 0;
    else if (a < 0.75f) q = 1;
    else if (a < 1.25f) q = 2;
    else if (a < 1.75f) q = 3;
    else if (a < 2.5f)  q = 4;
    else if (a < 3.5f)  q = 5;
    else if (a < 5.0f)  q = 6;
    else q = 7;
    return s | q;
}

// ---------------- weight pack: family layout ----------------
// Block gb (0..255): fam = gb>>7 (0: Wih0/Whh0, 1: Wih1/Whh1), blf = gb&127,
// features blf*16..+15. Per block 128KB: [m(2)][jt(4)=gate][kt(16)][lane(64)]x16B.
// scl per block 8KB: [m][jt][lane]x16 kt-bytes.
__global__ __launch_bounds__(256) void k_pack4(const float* __restrict__ W0, const float* __restrict__ W1,
                                               const float* __restrict__ W2, const float* __restrict__ W3,
                                               uchar* __restrict__ Wp4, uchar* __restrict__ scl) {
    __shared__ float lw[64][132];
    int idx = blockIdx.x;                 // [0, 8192): gb*32 + m*16 + kt
    int kt = idx & 15, m = (idx >> 4) & 1, gb = idx >> 5;
    int fam = gb >> 7, blf = gb & 127;
    const float* src = (fam == 0) ? (m == 0 ? W0 : W1) : (m == 0 ? W2 : W3);
    int tid = threadIdx.x;
    for (int i = tid; i < 64 * 32; i += 256) {
        int r = i >> 5, c4 = i & 31;       // r = jt*16 + fl
        const float* p = src + (size_t)((r >> 4) * 2048 + blf * 16 + (r & 15)) * 2048 + kt * 128 + c4 * 4;
        float4 v = *(const float4*)p;
        lw[r][c4 * 4 + 0] = v.x; lw[r][c4 * 4 + 1] = v.y;
        lw[r][c4 * 4 + 2] = v.z; lw[r][c4 * 4 + 3] = v.w;
    }
    __syncthreads();
    {
        int jt = tid >> 6, l = tid & 63;
        int r = jt * 16 + (l & 15);
        int k0 = (l >> 4) * 32;
        float mx = 0.f;
#pragma unroll
        for (int e = 0; e < 32; ++e) mx = fmaxf(mx, fabsf(lw[r][k0 + e]));
        int ee = -127;
        if (mx > 0.f) {
            ee = (int)ceilf(log2f(mx * (1.0f / 6.0f)));
            if (ee < -127) ee = -127;
            if (ee > 127) ee = 127;
        }
        float inv = exp2f((float)(-ee));
        unsigned wd[4];
#pragma unroll
        for (int d = 0; d < 4; ++d) {
            unsigned acc = 0;
#pragma unroll
            for (int bi = 0; bi < 4; ++bi) {
                float v0 = lw[r][k0 + d * 8 + 2 * bi] * inv;
                float v1 = lw[r][k0 + d * 8 + 2 * bi + 1] * inv;
                acc |= (q_e2m1(v0) << (bi * 8)) | (q_e2m1(v1) << (bi * 8 + 4));
            }
            wd[d] = acc;
        }
        size_t wo = (size_t)gb * 131072 + (size_t)((m * 4 + jt) * 16 + kt) * 1024 + (size_t)l * 16;
        *(uint4*)(Wp4 + wo) = make_uint4(wd[0], wd[1], wd[2], wd[3]);
        scl[(size_t)gb * 8192 + (size_t)((m * 4 + jt) * 64 + l) * 16 + kt] = (uchar)(ee + 127);
    }
}

__global__ void k_bias(const float* __restrict__ bi0, const float* __restrict__ bh0,
                       const float* __restrict__ bi1, const float* __restrict__ bh1,
                       float* __restrict__ bias0, float* __restrict__ bias1) {
    int i = blockIdx.x * blockDim.x + threadIdx.x;
    if (i < 4 * FDIM) {
        bias0[i] = bi0[i] + bh0[i];
        bias1[i] = bi1[i] + bh1[i];
    }
}

// ---------------- input 1x1 conv -> seq slots in MFMA-FRAGMENT layout, fp8 (x4) ----------------
__global__ __launch_bounds__(256) void k_seqprep(const float* __restrict__ x,
                                                 const float* __restrict__ w_in,
                                                 const float* __restrict__ b_in,
                                                 uchar* __restrict__ seqb) {
    int h = blockIdx.x >> 4, b = blockIdx.x & 15;
    __shared__ float xs[256][32];
    __shared__ float wl[64][257];
    int tid = threadIdx.x;
    for (int i = tid; i < 256 * 32; i += 256) {
        int c = i >> 5, w = i & 31;
        xs[c][w] = x[(((size_t)b * 256 + c) * 32 + h) * 32 + w];
    }
    for (int i = tid; i < 64 * 256; i += 256) {
        int cb = i >> 8, c = i & 255;
        wl[cb][c] = w_in[i];
    }
    __syncthreads();
    int w = (tid * 8) >> 6, cb0 = (tid * 8) & 63;
    float acc[8];
#pragma unroll
    for (int j = 0; j < 8; ++j) acc[j] = b_in[cb0 + j];
    for (int c = 0; c < 256; ++c) {
        float xv = xs[c][w];
#pragma unroll
        for (int j = 0; j < 8; ++j) acc[j] += xv * wl[cb0 + j][c];
    }
    unsigned lo = 0, hi2 = 0;
#pragma unroll
    for (int j = 0; j < 4; ++j) lo |= f2fp8(acc[j] * 4.0f) << (j * 8);
#pragma unroll
    for (int j = 0; j < 4; ++j) hi2 |= f2fp8(acc[4 + j] * 4.0f) << (j * 8);
    int kt = tid >> 4, kq = (tid >> 2) & 3, e0 = (tid & 3) * 8;
    uchar* dst = seqb + (size_t)h * SLOT + (size_t)kt * 2048 + (size_t)(b + 16 * kq) * 32 + e0;
    *(uint2*)dst = make_uint2(lo, hi2);
}

// ---------------- persistent LSTM: layer-family split pipeline ----------------
// Blocks 0..127 = L0 family (features blf*16..+15 of layer 0); 128..255 = L1 family.
// 9 waves: w0..7 compute (jp = w&1, kh = (w>>1)&1, m = w>>2); w8 poller.
// w6/w7 tails (features 0..7 / 8..15 local), independent half-tags.
__global__ __launch_bounds__(576, 1) void k_lstm(const uchar* __restrict__ Wp4,
                                                 const uchar* __restrict__ scl,
                                                 const float* __restrict__ bias0,
                                                 const float* __restrict__ bias1,
                                                 const uchar* __restrict__ seqb,
                                                 uchar* __restrict__ H0, uchar* __restrict__ H1,
                                                 u16* __restrict__ seqout,
                                                 unsigned* __restrict__ tags0,
                                                 unsigned* __restrict__ tags1) {
    __shared__ uchar wlds[131072];            // [m][jt][kt][lane*16]
    __shared__ float gbuf[4][4][16][16];      // [gate][m*2+kh][b][feat] partials (16KB)
    __shared__ u64 hs_st[16][2];
    __shared__ unsigned flag0LDS, flag1LDS;
    const int tid = threadIdx.x, lane = tid & 63, w = tid >> 6;
    const int jp = w & 1, kh = (w >> 1) & 1, m = w >> 2;  // valid for w<8
    const int bl = blockIdx.x;
    const int fam = bl >> 7, blf = bl & 127;

    {
        const uchar* src = Wp4 + (size_t)bl * 131072;
        for (int i = tid; i < 8192; i += 576)
            *(uint4*)(wlds + (size_t)i * 16) = *(const uint4*)(src + (size_t)i * 16);
    }
    // scale words for this wave's two gate-tiles (jt = jp*2, jp*2+1)
    unsigned sw00 = 0, sw01 = 0, sw10 = 0, sw11 = 0;
    if (w < 8) {
        const uchar* sbase = scl + (size_t)bl * 8192 + (size_t)((m * 4 + jp * 2) * 64 + lane) * 16;
        uint4 s0 = *(const uint4*)(sbase);
        uint4 s1 = *(const uint4*)(sbase + 1024);
        sw00 = kh ? s0.z : s0.x; sw01 = kh ? s0.w : s0.y;
        sw10 = kh ? s1.z : s1.x; sw11 = kh ? s1.w : s1.y;
    }
    // tail state (w6: local features 0..7, w7: 8..15); 2 (b,f) pairs per lane
    float bw[2][4];
    float cs[2] = {0.f, 0.f};
    const int wvoff = (w == 7) ? 8 : 0;
    if (w >= 6) {
        const int flb = (lane & 3) * 2;
        const float* barr = fam ? bias1 : bias0;
#pragma unroll
        for (int i = 0; i < 2; ++i) {
            int col = blf * 16 + wvoff + flb + i;
#pragma unroll
            for (int g = 0; g < 4; ++g) bw[i][g] = barr[g * FDIM + col];
        }
    }
    if (tid == 0) { flag0LDS = 0; flag1LDS = 0; }
    __syncthreads();

    unsigned f0 = 0, f1 = 0;   // poller progress (w8)
    const int b16 = lane & 15, kq = lane >> 4;

    for (int s = 0; s < NSTEP; ++s) {
        if (w == 8) {
            // verify tag rows in causal order, publish flags
            int t0 = fam ? (s + 1) : s;
            int t1 = fam ? s : ((s >= 32) ? s : 0);
#define ADV(F, TGT, TB, FL)                                                            \
            while ((int)F < (TGT)) {                                                   \
                const unsigned* trow = (TB) + (size_t)F * 2048;                        \
                for (;;) {                                                             \
                    unsigned v0 = __hip_atomic_load(trow + (size_t)lane * 8,           \
                                      __ATOMIC_RELAXED, __HIP_MEMORY_SCOPE_AGENT);     \
                    unsigned v1 = __hip_atomic_load(trow + (size_t)(lane + 64) * 8,    \
                                      __ATOMIC_RELAXED, __HIP_MEMORY_SCOPE_AGENT);     \
                    unsigned v2 = __hip_atomic_load(trow + (size_t)(lane + 128) * 8,   \
                                      __ATOMIC_RELAXED, __HIP_MEMORY_SCOPE_AGENT);     \
                    unsigned v3 = __hip_atomic_load(trow + (size_t)(lane + 192) * 8,   \
                                      __ATOMIC_RELAXED, __HIP_MEMORY_SCOPE_AGENT);     \
                    if ((v0 & v1 & v2 & v3) == 1u) break;                              \
                    __builtin_amdgcn_s_sleep(1);                                       \
                }                                                                      \
                ++F;                                                                   \
                if (lane == 0)                                                         \
                    __hip_atomic_store(&(FL), F, __ATOMIC_RELAXED,                     \
                                       __HIP_MEMORY_SCOPE_WORKGROUP);                  \
            }
            if (fam == 0) { ADV(f0, t0, tags0, flag0LDS) ADV(f1, t1, tags1, flag1LDS) }
            else          { ADV(f1, t1, tags1, flag1LDS) ADV(f0, t0, tags0, flag0LDS) }
#undef ADV
        } else {
            // dependency waits
            unsigned need0 = 0, need1 = 0;
            if (fam == 0) { if (m) need0 = (unsigned)s; else need1 = (s >= 32) ? (unsigned)s : 0u; }
            else          { if (m) need1 = (unsigned)s; else need0 = (unsigned)(s + 1); }
            if (need0)
                while (__hip_atomic_load(&flag0LDS, __ATOMIC_RELAXED,
                                         __HIP_MEMORY_SCOPE_WORKGROUP) < need0)
                    __builtin_amdgcn_s_sleep(1);
            if (need1)
                while (__hip_atomic_load(&flag1LDS, __ATOMIC_RELAXED,
                                         __HIP_MEMORY_SCOPE_WORKGROUP) < need1)
                    __builtin_amdgcn_s_sleep(1);
            asm volatile("" ::: "memory");

            const uchar* xsrc = fam ? (H0 + (size_t)(s + 1) * SLOT)
                              : (s < 32 ? seqb + (size_t)s * SLOT : H1 + (size_t)s * SLOT);
            const uchar* hsrc = fam ? (H1 + (size_t)s * SLOT) : (H0 + (size_t)s * SLOT);
            const uchar* asrc = m ? hsrc : xsrc;

            const uchar* ap = asrc + (size_t)lane * 32;
            uint4 A[8][2];
#pragma unroll
            for (int t = 0; t < 8; ++t) {
                A[t][0] = *(const uint4*)(ap + (size_t)(kh * 8 + t) * 2048);
                A[t][1] = *(const uint4*)(ap + (size_t)(kh * 8 + t) * 2048 + 16);
            }
            const uchar* bp0 = wlds + (size_t)((m * 4 + jp * 2) * 16 + kh * 8) * 1024 + lane * 16;
            const uchar* bp1 = bp0 + 16384;

            f32x4 aA0 = {0.f,0.f,0.f,0.f}, aA1 = {0.f,0.f,0.f,0.f};
            f32x4 aB0 = {0.f,0.f,0.f,0.f}, aB1 = {0.f,0.f,0.f,0.f};
#define MF(T)                                                                          \
            {                                                                          \
                uint4 alo = A[T][0], ahi = A[T][1];                                    \
                i8v av = {(int)alo.x, (int)alo.y, (int)alo.z, (int)alo.w,              \
                          (int)ahi.x, (int)ahi.y, (int)ahi.z, (int)ahi.w};             \
                uint4 b0 = *(const uint4*)(bp0 + (T) * 1024);                          \
                i8v bv0 = {(int)b0.x, (int)b0.y, (int)b0.z, (int)b0.w, 0, 0, 0, 0};    \
                uint4 b1 = *(const uint4*)(bp1 + (T) * 1024);                          \
                i8v bv1 = {(int)b1.x, (int)b1.y, (int)b1.z, (int)b1.w, 0, 0, 0, 0};    \
                if ((T) & 1) {                                                         \
                    aA1 = __builtin_amdgcn_mfma_scale_f32_16x16x128_f8f6f4(            \
                        av, bv0, aA1, 0, 4, 0, 127, (T) & 3,                           \
                        (int)((T) < 4 ? sw00 : sw01));                                 \
                    aB1 = __builtin_amdgcn_mfma_scale_f32_16x16x128_f8f6f4(            \
                        av, bv1, aB1, 0, 4, 0, 127, (T) & 3,                           \
                        (int)((T) < 4 ? sw10 : sw11));                                 \
                } else {                                                               \
                    aA0 = __builtin_amdgcn_mfma_scale_f32_16x16x128_f8f6f4(            \
                        av, bv0, aA0, 0, 4, 0, 127, (T) & 3,                           \
                        (int)((T) < 4 ? sw00 : sw01));                                 \
                    aB0 = __builtin_amdgcn_mfma_scale_f32_16x16x128_f8f6f4(            \
                        av, bv1, aB0, 0, 4, 0, 127, (T) & 3,                           \
                        (int)((T) < 4 ? sw10 : sw11));                                 \
                }                                                                      \
            }
            MF(0) MF(1) MF(2) MF(3) MF(4) MF(5) MF(6) MF(7)
#undef MF
            f32x4 rA = aA0 + aA1, rB = aB0 + aB1;
            const int slot = m * 2 + kh;
#pragma unroll
            for (int i = 0; i < 4; ++i) {
                gbuf[jp * 2 + 0][slot][kq * 4 + i][b16] = rA[i];
                gbuf[jp * 2 + 1][slot][kq * 4 + i][b16] = rB[i];
            }
        }
        __syncthreads();   // S1: all gbuf partials visible

        float gsum[2][4];
        if (w >= 6) {      // tails read gbuf before S2
            const int b = lane >> 2, flb = (lane & 3) * 2;
#pragma unroll
            for (int i = 0; i < 2; ++i) {
                const int f = wvoff + flb + i;
#pragma unroll
                for (int g = 0; g < 4; ++g)
                    gsum[i][g] = gbuf[g][0][b][f] + gbuf[g][1][b][f]
                               + gbuf[g][2][b][f] + gbuf[g][3][b][f];
            }
        }
        __syncthreads();   // S2: gbuf free for next iteration's writers

        if (w >= 6) {
            const int b = lane >> 2, flb = (lane & 3) * 2;
            u16 hb2 = 0;
            float hnv[2];
#pragma unroll
            for (int i = 0; i < 2; ++i) {
                float gv[4];
#pragma unroll
                for (int g = 0; g < 4; ++g) gv[g] = gsum[i][g] * 0.25f + bw[i][g];
                float cn = sigm(gv[1]) * cs[i] + sigm(gv[0]) * tanh_f(gv[2]);
                float hn = sigm(gv[3]) * tanh_f(cn);
                cs[i] = cn;
                hb2 |= (u16)(f2fp8(hn * 4.0f) << (8 * i));
                hnv[i] = hn;
            }
            const int wv = wvoff >> 3;
            *(u16*)((uchar*)&hs_st[b][wv] + flb) = hb2;
            asm volatile("s_waitcnt lgkmcnt(0)" ::: "memory");
            uchar* out = (fam ? H1 : H0) + (size_t)(s + 1) * SLOT;
            if (lane < 16) {
                const int kt0 = blf >> 3, sub = (blf & 7) >> 1, byte0 = (blf & 1) * 16;
                size_t o = (size_t)kt0 * 2048 + (size_t)(lane + 16 * sub) * 32 + byte0 + wvoff;
                __hip_atomic_store((u64*)(out + o), hs_st[lane][wv],
                                   __ATOMIC_RELAXED, __HIP_MEMORY_SCOPE_AGENT);
            }
            asm volatile("s_waitcnt vmcnt(0)" ::: "memory");   // h acked at L3
            if (lane == 0) {
                unsigned* tg = (fam ? tags1 : tags0) + (size_t)s * 2048 + (size_t)(blf * 2 + wv) * 8;
                __hip_atomic_store(tg, 1u, __ATOMIC_RELAXED, __HIP_MEMORY_SCOPE_AGENT);
            }
            if (fam && s >= 31) {   // L1 outputs (off the notify path)
                unsigned pk = (unsigned)f2b(hnv[0]) | ((unsigned)f2b(hnv[1]) << 16);
                *(unsigned*)(seqout + (size_t)(s - 31) * 16 * FDIM
                             + (size_t)b * FDIM + blf * 16 + wvoff + flb) = pk;
            }
        }
    }
}

// ---------------- copy x into top half of output ----------------
__global__ void k_copyx(const float* __restrict__ x, float* __restrict__ out) {
    size_t n = (size_t)4096 * 256;
    size_t stride = (size_t)gridDim.x * blockDim.x;
    for (size_t i = (size_t)blockIdx.x * blockDim.x + threadIdx.x; i < n; i += stride) {
        size_t bc = i >> 8, r = i & 255;
        ((float4*)out)[bc * 512 + r] = ((const float4*)x)[i];
    }
}

// ---------------- output 1x1 conv into bottom half ----------------
__global__ __launch_bounds__(256) void k_convout(const u16* __restrict__ seqout,
                                                 const float* __restrict__ w_out,
                                                 const float* __restrict__ b_out,
                                                 float* __restrict__ out) {
    int s = blockIdx.x >> 4, b = blockIdx.x & 15;
    __shared__ float srow[2048];
    int tid = threadIdx.x;
    for (int i = tid; i < 2048; i += 256) srow[i] = b2f(seqout[((size_t)s * 16 + b) * FDIM + i]);
    __syncthreads();
    int o = tid;
    float bo = b_out[o];
    float wreg[64];
#pragma unroll
    for (int cb = 0; cb < 64; ++cb) wreg[cb] = w_out[o * 64 + cb];
    for (int w4 = 0; w4 < 8; ++w4) {
        float ac0 = bo, ac1 = bo, ac2 = bo, ac3 = bo;
#pragma unroll
        for (int cb = 0; cb < 64; ++cb) {
            float wv = wreg[cb];
            ac0 += srow[(w4 * 4 + 0) * 64 + cb] * wv;
            ac1 += srow[(w4 * 4 + 1) * 64 + cb] * wv;
            ac2 += srow[(w4 * 4 + 2) * 64 + cb] * wv;
            ac3 += srow[(w4 * 4 + 3) * 64 + cb] * wv;
        }
        float4 v; v.x = ac0; v.y = ac1; v.z = ac2; v.w = ac3;
        *(float4*)&out[(((size_t)b * 256 + o) * 64 + 32 + s) * 32 + w4 * 4] = v;
    }
}

extern "C" void kernel_launch(void* const* d_in, const int* in_sizes, int n_in,
                              void* d_out, int out_size, void* d_ws, size_t ws_size,
                              hipStream_t stream) {
    const float* x    = (const float*)d_in[0];
    const float* w_in = (const float*)d_in[1];
    const float* b_in = (const float*)d_in[2];
    const float* Wih0 = (const float*)d_in[3];
    const float* Whh0 = (const float*)d_in[4];
    const float* bih0 = (const float*)d_in[5];
    const float* bhh0 = (const float*)d_in[6];
    const float* Wih1 = (const float*)d_in[7];
    const float* Whh1 = (const float*)d_in[8];
    const float* bih1 = (const float*)d_in[9];
    const float* bhh1 = (const float*)d_in[10];
    const float* wout = (const float*)d_in[11];
    const float* bout = (const float*)d_in[12];
    float* out = (float*)d_out;
    char* ws = (char*)d_ws;
    const size_t BF = (size_t)16 * FDIM;

    uchar* Wp4 = (uchar*)ws;
    size_t off = (size_t)NBLK * 131072;                        // 32 MiB packed fp4 weights
    uchar* scl = (uchar*)(ws + off); off += (size_t)NBLK * 8192;            // 2 MiB scales
    float* bias0 = (float*)(ws + off); off += 4 * FDIM * 4;
    float* bias1 = (float*)(ws + off); off += 4 * FDIM * 4;
    uchar* seqb = (uchar*)(ws + off); off += (size_t)32 * SLOT;             // 1 MiB
    u16* seqout = (u16*)(ws + off); off += (size_t)32 * BF * 2;             // 2 MiB
    uchar* H0 = (uchar*)(ws + off); off += (size_t)64 * SLOT;               // 2 MiB
    uchar* H1 = (uchar*)(ws + off); off += (size_t)64 * SLOT;               // 2 MiB
    off = (off + 127) & ~(size_t)127;
    unsigned* tags0 = (unsigned*)(ws + off); size_t tagoff = off;
    off += (size_t)NSTEP * 2048 * 4;                           // 63 rows x 256 half-tags x 32B
    unsigned* tags1 = (unsigned*)(ws + off);
    off += (size_t)NSTEP * 2048 * 4;

    // zero: H0 slot0, H1 slot0, both tag arrays (in-graph, every replay)
    hipMemsetAsync(H0, 0, SLOT, stream);
    hipMemsetAsync(H1, 0, SLOT, stream);
    hipMemsetAsync(ws + tagoff, 0, off - tagoff, stream);

    k_pack4<<<8192, 256, 0, stream>>>(Wih0, Whh0, Wih1, Whh1, Wp4, scl);
    k_bias<<<32, 256, 0, stream>>>(bih0, bhh0, bih1, bhh1, bias0, bias1);
    k_seqprep<<<512, 256, 0, stream>>>(x, w_in, b_in, seqb);
    k_lstm<<<NBLK, 576, 0, stream>>>(Wp4, scl, bias0, bias1, seqb, H0, H1, seqout, tags0, tags1);
    k_copyx<<<2048, 256, 0, stream>>>(x, out);
    k_convout<<<512, 256, 0, stream>>>(seqout, wout, bout, out);
}

// Round 13
// 603.699 us; speedup vs baseline: 2.5802x; 1.0279x over previous
//
#include <hip/hip_runtime.h>
#include <hip/hip_bf16.h>

typedef unsigned short u16;
typedef unsigned char uchar;
typedef unsigned long long u64;
typedef float f32x4 __attribute__((ext_vector_type(4)));
typedef int i8v __attribute__((ext_vector_type(8)));

#define FDIM 2048
#define NBLK 256
#define NSTEP 63
#define SLOT 32768   // bytes per h slot (16 x 2048 fp8)

__device__ __forceinline__ u16 f2b(float x) {
    __hip_bfloat16 h = __float2bfloat16(x);
    return __builtin_bit_cast(u16, h);
}
__device__ __forceinline__ float b2f(u16 u) {
    __hip_bfloat16 h = __builtin_bit_cast(__hip_bfloat16, u);
    return __bfloat162float(h);
}
__device__ __forceinline__ float sigm(float x) { return 1.0f / (1.0f + __expf(-x)); }
__device__ __forceinline__ float tanh_f(float x) { return 1.0f - 2.0f / (__expf(2.0f * x) + 1.0f); }

// OCP e4m3 encode (RNE), saturate to 448.
__device__ __forceinline__ unsigned f2fp8(float x) {
    unsigned u = __builtin_bit_cast(unsigned, x);
    unsigned s = (u >> 24) & 0x80u;
    unsigned mag = u & 0x7fffffffu;
    if (mag >= 0x43E80000u) return s | 0x7Eu;
    int e = (int)(mag >> 23) - 127;
    if (e >= -6) {
        unsigned m = mag + 0x7FFFFu + ((mag >> 20) & 1u);
        unsigned e8 = (m >> 23) - 127 + 7;
        unsigned m3 = (m >> 20) & 7u;
        if (e8 >= 16u) return s | 0x7Eu;
        return s | (e8 << 3) | m3;
    }
    float ax = __builtin_bit_cast(float, mag);
    int d = (int)__builtin_rintf(ax * 512.0f);
    return s | (unsigned)d;
}

// e2m1 (fp4) quantize (|v|<=6 after scaling)
__device__ __forceinline__ unsigned q_e2m1(float v) {
    unsigned s = (v < 0.f) ? 8u : 0u;
    float a = fabsf(v);
    unsigned q;
    if (a < 0.25f) q = 0;
    else if (a < 0.75f) q = 1;
    else if (a < 1.25f) q = 2;
    else if (a < 1.75f) q = 3;
    else if (a < 2.5f)  q = 4;
    else if (a < 3.5f)  q = 5;
    else if (a < 5.0f)  q = 6;
    else q = 7;
    return s | q;
}

// ---------------- weight pack: family layout ----------------
// Block gb (0..255): fam = gb>>7 (0: Wih0/Whh0, 1: Wih1/Whh1), blf = gb&127,
// features blf*16..+15. Per block 128KB: [m(2)][jt(4)=gate][kt(16)][lane(64)]x16B.
// scl per block 8KB: [m][jt][lane]x16 kt-bytes.
__global__ __launch_bounds__(256) void k_pack4(const float* __restrict__ W0, const float* __restrict__ W1,
                                               const float* __restrict__ W2, const float* __restrict__ W3,
                                               uchar* __restrict__ Wp4, uchar* __restrict__ scl) {
    __shared__ float lw[64][132];
    int idx = blockIdx.x;                 // [0, 8192): gb*32 + m*16 + kt
    int kt = idx & 15, m = (idx >> 4) & 1, gb = idx >> 5;
    int fam = gb >> 7, blf = gb & 127;
    const float* src = (fam == 0) ? (m == 0 ? W0 : W1) : (m == 0 ? W2 : W3);
    int tid = threadIdx.x;
    for (int i = tid; i < 64 * 32; i += 256) {
        int r = i >> 5, c4 = i & 31;       // r = jt*16 + fl
        const float* p = src + (size_t)((r >> 4) * 2048 + blf * 16 + (r & 15)) * 2048 + kt * 128 + c4 * 4;
        float4 v = *(const float4*)p;
        lw[r][c4 * 4 + 0] = v.x; lw[r][c4 * 4 + 1] = v.y;
        lw[r][c4 * 4 + 2] = v.z; lw[r][c4 * 4 + 3] = v.w;
    }
    __syncthreads();
    {
        int jt = tid >> 6, l = tid & 63;
        int r = jt * 16 + (l & 15);
        int k0 = (l >> 4) * 32;
        float mx = 0.f;
#pragma unroll
        for (int e = 0; e < 32; ++e) mx = fmaxf(mx, fabsf(lw[r][k0 + e]));
        int ee = -127;
        if (mx > 0.f) {
            ee = (int)ceilf(log2f(mx * (1.0f / 6.0f)));
            if (ee < -127) ee = -127;
            if (ee > 127) ee = 127;
        }
        float inv = exp2f((float)(-ee));
        unsigned wd[4];
#pragma unroll
        for (int d = 0; d < 4; ++d) {
            unsigned acc = 0;
#pragma unroll
            for (int bi = 0; bi < 4; ++bi) {
                float v0 = lw[r][k0 + d * 8 + 2 * bi] * inv;
                float v1 = lw[r][k0 + d * 8 + 2 * bi + 1] * inv;
                acc |= (q_e2m1(v0) << (bi * 8)) | (q_e2m1(v1) << (bi * 8 + 4));
            }
            wd[d] = acc;
        }
        size_t wo = (size_t)gb * 131072 + (size_t)((m * 4 + jt) * 16 + kt) * 1024 + (size_t)l * 16;
        *(uint4*)(Wp4 + wo) = make_uint4(wd[0], wd[1], wd[2], wd[3]);
        scl[(size_t)gb * 8192 + (size_t)((m * 4 + jt) * 64 + l) * 16 + kt] = (uchar)(ee + 127);
    }
}

__global__ void k_bias(const float* __restrict__ bi0, const float* __restrict__ bh0,
                       const float* __restrict__ bi1, const float* __restrict__ bh1,
                       float* __restrict__ bias0, float* __restrict__ bias1) {
    int i = blockIdx.x * blockDim.x + threadIdx.x;
    if (i < 4 * FDIM) {
        bias0[i] = bi0[i] + bh0[i];
        bias1[i] = bi1[i] + bh1[i];
    }
}

// ---------------- input 1x1 conv -> seq slots in MFMA-FRAGMENT layout, fp8 (x4) ----------------
__global__ __launch_bounds__(256) void k_seqprep(const float* __restrict__ x,
                                                 const float* __restrict__ w_in,
                                                 const float* __restrict__ b_in,
                                                 uchar* __restrict__ seqb) {
    int h = blockIdx.x >> 4, b = blockIdx.x & 15;
    __shared__ float xs[256][32];
    __shared__ float wl[64][257];
    int tid = threadIdx.x;
    for (int i = tid; i < 256 * 32; i += 256) {
        int c = i >> 5, w = i & 31;
        xs[c][w] = x[(((size_t)b * 256 + c) * 32 + h) * 32 + w];
    }
    for (int i = tid; i < 64 * 256; i += 256) {
        int cb = i >> 8, c = i & 255;
        wl[cb][c] = w_in[i];
    }
    __syncthreads();
    int w = (tid * 8) >> 6, cb0 = (tid * 8) & 63;
    float acc[8];
#pragma unroll
    for (int j = 0; j < 8; ++j) acc[j] = b_in[cb0 + j];
    for (int c = 0; c < 256; ++c) {
        float xv = xs[c][w];
#pragma unroll
        for (int j = 0; j < 8; ++j) acc[j] += xv * wl[cb0 + j][c];
    }
    unsigned lo = 0, hi2 = 0;
#pragma unroll
    for (int j = 0; j < 4; ++j) lo |= f2fp8(acc[j] * 4.0f) << (j * 8);
#pragma unroll
    for (int j = 0; j < 4; ++j) hi2 |= f2fp8(acc[4 + j] * 4.0f) << (j * 8);
    int kt = tid >> 4, kq = (tid >> 2) & 3, e0 = (tid & 3) * 8;
    uchar* dst = seqb + (size_t)h * SLOT + (size_t)kt * 2048 + (size_t)(b + 16 * kq) * 32 + e0;
    *(uint2*)dst = make_uint2(lo, hi2);
}

// ---------------- persistent LSTM: layer-family split, low-pressure tag protocol ----------------
// Blocks 0..127 = L0 family; 128..255 = L1 family. 9 waves: w0..7 compute
// (jp = w&1, kh = (w>>1)&1, m = w>>2); w8 poller. w6/w7 tails; ONE tag per block
// (w6 drains -> LDS flag; w7 drains, waits flag, stores tag). Tags 128B apart;
// poller lanes wait on their OWN 2 tags with s_sleep(4) backoff.
__global__ __launch_bounds__(576, 1) void k_lstm(const uchar* __restrict__ Wp4,
                                                 const uchar* __restrict__ scl,
                                                 const float* __restrict__ bias0,
                                                 const float* __restrict__ bias1,
                                                 const uchar* __restrict__ seqb,
                                                 uchar* __restrict__ H0, uchar* __restrict__ H1,
                                                 u16* __restrict__ seqout,
                                                 unsigned* __restrict__ tags0,
                                                 unsigned* __restrict__ tags1) {
    __shared__ uchar wlds[131072];            // [m][jt][kt][lane*16]
    __shared__ float gbuf[4][4][16][16];      // [gate][m*2+kh][b][feat] partials (16KB)
    __shared__ u64 hs_st[16][2];
    __shared__ unsigned flag0LDS, flag1LDS, w6done;
    const int tid = threadIdx.x, lane = tid & 63, w = tid >> 6;
    const int jp = w & 1, kh = (w >> 1) & 1, m = w >> 2;  // valid for w<8
    const int bl = blockIdx.x;
    const int fam = bl >> 7, blf = bl & 127;

    {
        const uchar* src = Wp4 + (size_t)bl * 131072;
        for (int i = tid; i < 8192; i += 576)
            *(uint4*)(wlds + (size_t)i * 16) = *(const uint4*)(src + (size_t)i * 16);
    }
    unsigned sw00 = 0, sw01 = 0, sw10 = 0, sw11 = 0;
    if (w < 8) {
        const uchar* sbase = scl + (size_t)bl * 8192 + (size_t)((m * 4 + jp * 2) * 64 + lane) * 16;
        uint4 s0 = *(const uint4*)(sbase);
        uint4 s1 = *(const uint4*)(sbase + 1024);
        sw00 = kh ? s0.z : s0.x; sw01 = kh ? s0.w : s0.y;
        sw10 = kh ? s1.z : s1.x; sw11 = kh ? s1.w : s1.y;
    }
    // tail state (w6: local features 0..7, w7: 8..15); 2 (b,f) pairs per lane
    float bw[2][4];
    float cs[2] = {0.f, 0.f};
    const int wvoff = (w == 7) ? 8 : 0;
    if (w >= 6) {
        const int flb = (lane & 3) * 2;
        const float* barr = fam ? bias1 : bias0;
#pragma unroll
        for (int i = 0; i < 2; ++i) {
            int col = blf * 16 + wvoff + flb + i;
#pragma unroll
            for (int g = 0; g < 4; ++g) bw[i][g] = barr[g * FDIM + col];
        }
    }
    if (tid == 0) { flag0LDS = 0; flag1LDS = 0; w6done = 0; }
    __syncthreads();

    unsigned f0 = 0, f1 = 0;   // poller progress (w8)
    const int b16 = lane & 15, kq = lane >> 4;

    for (int s = 0; s < NSTEP; ++s) {
        if (w == 8) {
            // verify tag rows in causal order; per-lane waits with backoff
            int t0 = fam ? (s + 1) : s;
            int t1 = fam ? s : ((s >= 32) ? s : 0);
#define ADV(F, TGT, TB, FL)                                                            \
            while ((int)F < (TGT)) {                                                   \
                const unsigned* trow = (TB) + (size_t)F * 4096;                        \
                const unsigned* t0p = trow + (size_t)lane * 32;                        \
                const unsigned* t1p = trow + (size_t)(lane + 64) * 32;                 \
                while (__hip_atomic_load(t0p, __ATOMIC_RELAXED,                        \
                                         __HIP_MEMORY_SCOPE_AGENT) != 1u)              \
                    __builtin_amdgcn_s_sleep(4);                                       \
                while (__hip_atomic_load(t1p, __ATOMIC_RELAXED,                        \
                                         __HIP_MEMORY_SCOPE_AGENT) != 1u)              \
                    __builtin_amdgcn_s_sleep(4);                                       \
                ++F;                                                                   \
                if (lane == 0)                                                         \
                    __hip_atomic_store(&(FL), F, __ATOMIC_RELAXED,                     \
                                       __HIP_MEMORY_SCOPE_WORKGROUP);                  \
            }
            if (fam == 0) { ADV(f0, t0, tags0, flag0LDS) ADV(f1, t1, tags1, flag1LDS) }
            else          { ADV(f1, t1, tags1, flag1LDS) ADV(f0, t0, tags0, flag0LDS) }
#undef ADV
        } else {
            // dependency waits
            unsigned need0 = 0, need1 = 0;
            if (fam == 0) { if (m) need0 = (unsigned)s; else need1 = (s >= 32) ? (unsigned)s : 0u; }
            else          { if (m) need1 = (unsigned)s; else need0 = (unsigned)(s + 1); }
            if (need0)
                while (__hip_atomic_load(&flag0LDS, __ATOMIC_RELAXED,
                                         __HIP_MEMORY_SCOPE_WORKGROUP) < need0)
                    __builtin_amdgcn_s_sleep(1);
            if (need1)
                while (__hip_atomic_load(&flag1LDS, __ATOMIC_RELAXED,
                                         __HIP_MEMORY_SCOPE_WORKGROUP) < need1)
                    __builtin_amdgcn_s_sleep(1);
            asm volatile("" ::: "memory");

            const uchar* xsrc = fam ? (H0 + (size_t)(s + 1) * SLOT)
                              : (s < 32 ? seqb + (size_t)s * SLOT : H1 + (size_t)s * SLOT);
            const uchar* hsrc = fam ? (H1 + (size_t)s * SLOT) : (H0 + (size_t)s * SLOT);
            const uchar* asrc = m ? hsrc : xsrc;

            const uchar* ap = asrc + (size_t)lane * 32;
            uint4 A[8][2];
#pragma unroll
            for (int t = 0; t < 8; ++t) {
                A[t][0] = *(const uint4*)(ap + (size_t)(kh * 8 + t) * 2048);
                A[t][1] = *(const uint4*)(ap + (size_t)(kh * 8 + t) * 2048 + 16);
            }
            const uchar* bp0 = wlds + (size_t)((m * 4 + jp * 2) * 16 + kh * 8) * 1024 + lane * 16;
            const uchar* bp1 = bp0 + 16384;

            f32x4 aA0 = {0.f,0.f,0.f,0.f}, aA1 = {0.f,0.f,0.f,0.f};
            f32x4 aB0 = {0.f,0.f,0.f,0.f}, aB1 = {0.f,0.f,0.f,0.f};
#define MF(T)                                                                          \
            {                                                                          \
                uint4 alo = A[T][0], ahi = A[T][1];                                    \
                i8v av = {(int)alo.x, (int)alo.y, (int)alo.z, (int)alo.w,              \
                          (int)ahi.x, (int)ahi.y, (int)ahi.z, (int)ahi.w};             \
                uint4 b0 = *(const uint4*)(bp0 + (T) * 1024);                          \
                i8v bv0 = {(int)b0.x, (int)b0.y, (int)b0.z, (int)b0.w, 0, 0, 0, 0};    \
                uint4 b1 = *(const uint4*)(bp1 + (T) * 1024);                          \
                i8v bv1 = {(int)b1.x, (int)b1.y, (int)b1.z, (int)b1.w, 0, 0, 0, 0};    \
                if ((T) & 1) {                                                         \
                    aA1 = __builtin_amdgcn_mfma_scale_f32_16x16x128_f8f6f4(            \
                        av, bv0, aA1, 0, 4, 0, 127, (T) & 3,                           \
                        (int)((T) < 4 ? sw00 : sw01));                                 \
                    aB1 = __builtin_amdgcn_mfma_scale_f32_16x16x128_f8f6f4(            \
                        av, bv1, aB1, 0, 4, 0, 127, (T) & 3,                           \
                        (int)((T) < 4 ? sw10 : sw11));                                 \
                } else {                                                               \
                    aA0 = __builtin_amdgcn_mfma_scale_f32_16x16x128_f8f6f4(            \
                        av, bv0, aA0, 0, 4, 0, 127, (T) & 3,                           \
                        (int)((T) < 4 ? sw00 : sw01));                                 \
                    aB0 = __builtin_amdgcn_mfma_scale_f32_16x16x128_f8f6f4(            \
                        av, bv1, aB0, 0, 4, 0, 127, (T) & 3,                           \
                        (int)((T) < 4 ? sw10 : sw11));                                 \
                }                                                                      \
            }
            MF(0) MF(1) MF(2) MF(3) MF(4) MF(5) MF(6) MF(7)
#undef MF
            f32x4 rA = aA0 + aA1, rB = aB0 + aB1;
            const int slot = m * 2 + kh;
#pragma unroll
            for (int i = 0; i < 4; ++i) {
                gbuf[jp * 2 + 0][slot][kq * 4 + i][b16] = rA[i];
                gbuf[jp * 2 + 1][slot][kq * 4 + i][b16] = rB[i];
            }
        }
        __syncthreads();   // S1: all gbuf partials visible

        float gsum[2][4];
        if (w >= 6) {      // tails read gbuf before S2
            const int b = lane >> 2, flb = (lane & 3) * 2;
#pragma unroll
            for (int i = 0; i < 2; ++i) {
                const int f = wvoff + flb + i;
#pragma unroll
                for (int g = 0; g < 4; ++g)
                    gsum[i][g] = gbuf[g][0][b][f] + gbuf[g][1][b][f]
                               + gbuf[g][2][b][f] + gbuf[g][3][b][f];
            }
        }
        __syncthreads();   // S2: gbuf free for next iteration's writers

        if (w >= 6) {
            const int b = lane >> 2, flb = (lane & 3) * 2;
            u16 hb2 = 0;
            float hnv[2];
#pragma unroll
            for (int i = 0; i < 2; ++i) {
                float gv[4];
#pragma unroll
                for (int g = 0; g < 4; ++g) gv[g] = gsum[i][g] * 0.25f + bw[i][g];
                float cn = sigm(gv[1]) * cs[i] + sigm(gv[0]) * tanh_f(gv[2]);
                float hn = sigm(gv[3]) * tanh_f(cn);
                cs[i] = cn;
                hb2 |= (u16)(f2fp8(hn * 4.0f) << (8 * i));
                hnv[i] = hn;
            }
            const int wv = wvoff >> 3;
            *(u16*)((uchar*)&hs_st[b][wv] + flb) = hb2;
            asm volatile("s_waitcnt lgkmcnt(0)" ::: "memory");
            uchar* out = (fam ? H1 : H0) + (size_t)(s + 1) * SLOT;
            if (lane < 16) {
                const int kt0 = blf >> 3, sub = (blf & 7) >> 1, byte0 = (blf & 1) * 16;
                size_t o = (size_t)kt0 * 2048 + (size_t)(lane + 16 * sub) * 32 + byte0 + wvoff;
                __hip_atomic_store((u64*)(out + o), hs_st[lane][wv],
                                   __ATOMIC_RELAXED, __HIP_MEMORY_SCOPE_AGENT);
            }
            asm volatile("s_waitcnt vmcnt(0)" ::: "memory");   // own h-half acked at L3
            if (w == 6) {
                if (lane == 0)
                    __hip_atomic_store(&w6done, (unsigned)(s + 1),
                                       __ATOMIC_RELAXED, __HIP_MEMORY_SCOPE_WORKGROUP);
            } else {
                if (lane == 0) {
                    while (__hip_atomic_load(&w6done, __ATOMIC_RELAXED,
                                             __HIP_MEMORY_SCOPE_WORKGROUP) < (unsigned)(s + 1))
                        ;   // short LDS spin: w6 drains concurrently
                    unsigned* tg = (fam ? tags1 : tags0) + (size_t)s * 4096 + (size_t)blf * 32;
                    __hip_atomic_store(tg, 1u, __ATOMIC_RELAXED, __HIP_MEMORY_SCOPE_AGENT);
                }
            }
            if (fam && s >= 31) {   // L1 outputs (off the notify path)
                unsigned pk = (unsigned)f2b(hnv[0]) | ((unsigned)f2b(hnv[1]) << 16);
                *(unsigned*)(seqout + (size_t)(s - 31) * 16 * FDIM
                             + (size_t)b * FDIM + blf * 16 + wvoff + flb) = pk;
            }
        }
    }
}

// ---------------- copy x into top half of output ----------------
__global__ void k_copyx(const float* __restrict__ x, float* __restrict__ out) {
    size_t n = (size_t)4096 * 256;
    size_t stride = (size_t)gridDim.x * blockDim.x;
    for (size_t i = (size_t)blockIdx.x * blockDim.x + threadIdx.x; i < n; i += stride) {
        size_t bc = i >> 8, r = i & 255;
        ((float4*)out)[bc * 512 + r] = ((const float4*)x)[i];
    }
}

// ---------------- output 1x1 conv into bottom half ----------------
__global__ __launch_bounds__(256) void k_convout(const u16* __restrict__ seqout,
                                                 const float* __restrict__ w_out,
                                                 const float* __restrict__ b_out,
                                                 float* __restrict__ out) {
    int s = blockIdx.x >> 4, b = blockIdx.x & 15;
    __shared__ float srow[2048];
    int tid = threadIdx.x;
    for (int i = tid; i < 2048; i += 256) srow[i] = b2f(seqout[((size_t)s * 16 + b) * FDIM + i]);
    __syncthreads();
    int o = tid;
    float bo = b_out[o];
    float wreg[64];
#pragma unroll
    for (int cb = 0; cb < 64; ++cb) wreg[cb] = w_out[o * 64 + cb];
    for (int w4 = 0; w4 < 8; ++w4) {
        float ac0 = bo, ac1 = bo, ac2 = bo, ac3 = bo;
#pragma unroll
        for (int cb = 0; cb < 64; ++cb) {
            float wv = wreg[cb];
            ac0 += srow[(w4 * 4 + 0) * 64 + cb] * wv;
            ac1 += srow[(w4 * 4 + 1) * 64 + cb] * wv;
            ac2 += srow[(w4 * 4 + 2) * 64 + cb] * wv;
            ac3 += srow[(w4 * 4 + 3) * 64 + cb] * wv;
        }
        float4 v; v.x = ac0; v.y = ac1; v.z = ac2; v.w = ac3;
        *(float4*)&out[(((size_t)b * 256 + o) * 64 + 32 + s) * 32 + w4 * 4] = v;
    }
}

extern "C" void kernel_launch(void* const* d_in, const int* in_sizes, int n_in,
                              void* d_out, int out_size, void* d_ws, size_t ws_size,
                              hipStream_t stream) {
    const float* x    = (const float*)d_in[0];
    const float* w_in = (const float*)d_in[1];
    const float* b_in = (const float*)d_in[2];
    const float* Wih0 = (const float*)d_in[3];
    const float* Whh0 = (const float*)d_in[4];
    const float* bih0 = (const float*)d_in[5];
    const float* bhh0 = (const float*)d_in[6];
    const float* Wih1 = (const float*)d_in[7];
    const float* Whh1 = (const float*)d_in[8];
    const float* bih1 = (const float*)d_in[9];
    const float* bhh1 = (const float*)d_in[10];
    const float* wout = (const float*)d_in[11];
    const float* bout = (const float*)d_in[12];
    float* out = (float*)d_out;
    char* ws = (char*)d_ws;
    const size_t BF = (size_t)16 * FDIM;

    uchar* Wp4 = (uchar*)ws;
    size_t off = (size_t)NBLK * 131072;                        // 32 MiB packed fp4 weights
    uchar* scl = (uchar*)(ws + off); off += (size_t)NBLK * 8192;            // 2 MiB scales
    float* bias0 = (float*)(ws + off); off += 4 * FDIM * 4;
    float* bias1 = (float*)(ws + off); off += 4 * FDIM * 4;
    uchar* seqb = (uchar*)(ws + off); off += (size_t)32 * SLOT;             // 1 MiB
    u16* seqout = (u16*)(ws + off); off += (size_t)32 * BF * 2;             // 2 MiB
    uchar* H0 = (uchar*)(ws + off); off += (size_t)64 * SLOT;               // 2 MiB
    uchar* H1 = (uchar*)(ws + off); off += (size_t)64 * SLOT;               // 2 MiB
    off = (off + 127) & ~(size_t)127;
    unsigned* tags0 = (unsigned*)(ws + off); size_t tagoff = off;
    off += (size_t)NSTEP * 4096 * 4;                           // 63 rows x 128 tags x 128B
    unsigned* tags1 = (unsigned*)(ws + off);
    off += (size_t)NSTEP * 4096 * 4;

    // zero: H0 slot0, H1 slot0, both tag arrays (in-graph, every replay)
    hipMemsetAsync(H0, 0, SLOT, stream);
    hipMemsetAsync(H1, 0, SLOT, stream);
    hipMemsetAsync(ws + tagoff, 0, off - tagoff, stream);

    k_pack4<<<8192, 256, 0, stream>>>(Wih0, Whh0, Wih1, Whh1, Wp4, scl);
    k_bias<<<32, 256, 0, stream>>>(bih0, bhh0, bih1, bhh1, bias0, bias1);
    k_seqprep<<<512, 256, 0, stream>>>(x, w_in, b_in, seqb);
    k_lstm<<<NBLK, 576, 0, stream>>>(Wp4, scl, bias0, bias1, seqb, H0, H1, seqout, tags0, tags1);
    k_copyx<<<2048, 256, 0, stream>>>(x, out);
    k_convout<<<512, 256, 0, stream>>>(seqout, wout, bout, out);
}

// Round 14
// 584.150 us; speedup vs baseline: 2.6665x; 1.0335x over previous
//
#include <hip/hip_runtime.h>
#include <hip/hip_bf16.h>

typedef unsigned short u16;
typedef unsigned char uchar;
typedef unsigned long long u64;
typedef float f32x4 __attribute__((ext_vector_type(4)));
typedef int i8v __attribute__((ext_vector_type(8)));

#define FDIM 2048
#define NBLK 256
#define NSTEP 63
#define SLOT 32768   // bytes per h slot (16 x 2048 fp8)

__device__ __forceinline__ u16 f2b(float x) {
    __hip_bfloat16 h = __float2bfloat16(x);
    return __builtin_bit_cast(u16, h);
}
__device__ __forceinline__ float b2f(u16 u) {
    __hip_bfloat16 h = __builtin_bit_cast(__hip_bfloat16, u);
    return __bfloat162float(h);
}
__device__ __forceinline__ float sigm(float x) { return 1.0f / (1.0f + __expf(-x)); }
__device__ __forceinline__ float tanh_f(float x) { return 1.0f - 2.0f / (__expf(2.0f * x) + 1.0f); }

// OCP e4m3 encode (RNE), saturate to 448.
__device__ __forceinline__ unsigned f2fp8(float x) {
    unsigned u = __builtin_bit_cast(unsigned, x);
    unsigned s = (u >> 24) & 0x80u;
    unsigned mag = u & 0x7fffffffu;
    if (mag >= 0x43E80000u) return s | 0x7Eu;
    int e = (int)(mag >> 23) - 127;
    if (e >= -6) {
        unsigned m = mag + 0x7FFFFu + ((mag >> 20) & 1u);
        unsigned e8 = (m >> 23) - 127 + 7;
        unsigned m3 = (m >> 20) & 7u;
        if (e8 >= 16u) return s | 0x7Eu;
        return s | (e8 << 3) | m3;
    }
    float ax = __builtin_bit_cast(float, mag);
    int d = (int)__builtin_rintf(ax * 512.0f);
    return s | (unsigned)d;
}

// e2m1 (fp4) quantize (|v|<=6 after scaling)
__device__ __forceinline__ unsigned q_e2m1(float v) {
    unsigned s = (v < 0.f) ? 8u : 0u;
    float a = fabsf(v);
    unsigned q;
    if (a < 0.25f) q = 0;
    else if (a < 0.75f) q = 1;
    else if (a < 1.25f) q = 2;
    else if (a < 1.75f) q = 3;
    else if (a < 2.5f)  q = 4;
    else if (a < 3.5f)  q = 5;
    else if (a < 5.0f)  q = 6;
    else q = 7;
    return s | q;
}

// ---------------- input 1x1 conv -> seq slots in MFMA-FRAGMENT layout, fp8 (x4) ----------------
__global__ __launch_bounds__(256) void k_seqprep(const float* __restrict__ x,
                                                 const float* __restrict__ w_in,
                                                 const float* __restrict__ b_in,
                                                 uchar* __restrict__ seqb) {
    int h = blockIdx.x >> 4, b = blockIdx.x & 15;
    __shared__ float xs[256][32];
    __shared__ float wl[64][257];
    int tid = threadIdx.x;
    for (int i = tid; i < 256 * 32; i += 256) {
        int c = i >> 5, w = i & 31;
        xs[c][w] = x[(((size_t)b * 256 + c) * 32 + h) * 32 + w];
    }
    for (int i = tid; i < 64 * 256; i += 256) {
        int cb = i >> 8, c = i & 255;
        wl[cb][c] = w_in[i];
    }
    __syncthreads();
    int w = (tid * 8) >> 6, cb0 = (tid * 8) & 63;
    float acc[8];
#pragma unroll
    for (int j = 0; j < 8; ++j) acc[j] = b_in[cb0 + j];
    for (int c = 0; c < 256; ++c) {
        float xv = xs[c][w];
#pragma unroll
        for (int j = 0; j < 8; ++j) acc[j] += xv * wl[cb0 + j][c];
    }
    unsigned lo = 0, hi2 = 0;
#pragma unroll
    for (int j = 0; j < 4; ++j) lo |= f2fp8(acc[j] * 4.0f) << (j * 8);
#pragma unroll
    for (int j = 0; j < 4; ++j) hi2 |= f2fp8(acc[4 + j] * 4.0f) << (j * 8);
    int kt = tid >> 4, kq = (tid >> 2) & 3, e0 = (tid & 3) * 8;
    uchar* dst = seqb + (size_t)h * SLOT + (size_t)kt * 2048 + (size_t)(b + 16 * kq) * 32 + e0;
    *(uint2*)dst = make_uint2(lo, hi2);
}

// ---------------- persistent LSTM: all-in-one ----------------
// Prologue: each block packs its own fp32 weights -> fp4 MX in LDS (k_pack4 math verbatim).
// Blocks 0..127 = L0 family; 128..255 = L1 family. 9 waves: w0..7 compute
// (jp = w&1, kh = (w>>1)&1, m = w>>2); w8 poller; w6/w7 tails (single tag via w6done);
// w4/w5 steal x->out copy chunks while waiting on their flag (idle-BW harvesting).
__global__ __launch_bounds__(576, 1) void k_lstm(const float* __restrict__ Wih0,
                                                 const float* __restrict__ Whh0,
                                                 const float* __restrict__ Wih1,
                                                 const float* __restrict__ Whh1,
                                                 const float* __restrict__ bih0,
                                                 const float* __restrict__ bhh0,
                                                 const float* __restrict__ bih1,
                                                 const float* __restrict__ bhh1,
                                                 const uchar* __restrict__ seqb,
                                                 uchar* __restrict__ H0, uchar* __restrict__ H1,
                                                 u16* __restrict__ seqout,
                                                 unsigned* __restrict__ tags0,
                                                 unsigned* __restrict__ tags1,
                                                 const float* __restrict__ xg,
                                                 float* __restrict__ outg) {
    __shared__ uchar wlds[131072];            // [m][jt][kt][lane*16] fp4 packed
    __shared__ uchar sclLDS[8192];            // [m][jt][lane]x16 kt scale bytes
    __shared__ float gbuf[4][4][16][16];      // [gate][m*2+kh][b][feat] partials (16KB)
    __shared__ u64 hs_st[16][2];
    __shared__ unsigned flag0LDS, flag1LDS, w6done;
    const int tid = threadIdx.x, lane = tid & 63, w = tid >> 6;
    const int jp = w & 1, kh = (w >> 1) & 1, m = w >> 2;  // valid for w<8
    const int bl = blockIdx.x;
    const int fam = bl >> 7, blf = bl & 127;

    // ---- prologue: pack this block's weights fp32 -> fp4 MX directly into LDS ----
    {
        const float* srcA = fam ? Wih1 : Wih0;   // mm = 0
        const float* srcB = fam ? Whh1 : Whh0;   // mm = 1
        for (int e = tid; e < 8192; e += 576) {
            int l = e & 63, kt = (e >> 6) & 15, jt = (e >> 10) & 3, mm = e >> 12;
            const float* src = mm ? srcB : srcA;
            const float* p = src + (size_t)(jt * 2048 + blf * 16 + (l & 15)) * 2048
                           + kt * 128 + (l >> 4) * 32;
            float v[32];
#pragma unroll
            for (int j = 0; j < 8; ++j) {
                float4 q = *(const float4*)(p + j * 4);
                v[j * 4 + 0] = q.x; v[j * 4 + 1] = q.y;
                v[j * 4 + 2] = q.z; v[j * 4 + 3] = q.w;
            }
            float mx = 0.f;
#pragma unroll
            for (int ei = 0; ei < 32; ++ei) mx = fmaxf(mx, fabsf(v[ei]));
            int ee = -127;
            if (mx > 0.f) {
                ee = (int)ceilf(log2f(mx * (1.0f / 6.0f)));
                if (ee < -127) ee = -127;
                if (ee > 127) ee = 127;
            }
            float inv = exp2f((float)(-ee));
            unsigned wd[4];
#pragma unroll
            for (int d = 0; d < 4; ++d) {
                unsigned acc = 0;
#pragma unroll
                for (int bi = 0; bi < 4; ++bi) {
                    float v0 = v[d * 8 + 2 * bi] * inv;
                    float v1 = v[d * 8 + 2 * bi + 1] * inv;
                    acc |= (q_e2m1(v0) << (bi * 8)) | (q_e2m1(v1) << (bi * 8 + 4));
                }
                wd[d] = acc;
            }
            *(uint4*)(wlds + (size_t)e * 16) = make_uint4(wd[0], wd[1], wd[2], wd[3]);
            sclLDS[(size_t)((mm * 4 + jt) * 64 + l) * 16 + kt] = (uchar)(ee + 127);
        }
    }
    if (tid == 0) { flag0LDS = 0; flag1LDS = 0; w6done = 0; }
    __syncthreads();

    unsigned sw00 = 0, sw01 = 0, sw10 = 0, sw11 = 0;
    if (w < 8) {
        const uchar* sbase = sclLDS + (size_t)((m * 4 + jp * 2) * 64 + lane) * 16;
        uint4 s0 = *(const uint4*)(sbase);
        uint4 s1 = *(const uint4*)(sbase + 1024);
        sw00 = kh ? s0.z : s0.x; sw01 = kh ? s0.w : s0.y;
        sw10 = kh ? s1.z : s1.x; sw11 = kh ? s1.w : s1.y;
    }
    // tail state (w6: local features 0..7, w7: 8..15); 2 (b,f) pairs per lane
    float bw[2][4];
    float cs[2] = {0.f, 0.f};
    const int wvoff = (w == 7) ? 8 : 0;
    if (w >= 6) {
        const int flb = (lane & 3) * 2;
        const float* bi_ = fam ? bih1 : bih0;
        const float* bh_ = fam ? bhh1 : bhh0;
#pragma unroll
        for (int i = 0; i < 2; ++i) {
            int col = blf * 16 + wvoff + flb + i;
#pragma unroll
            for (int g = 0; g < 4; ++g)
                bw[i][g] = bi_[g * FDIM + col] + bh_[g * FDIM + col];
        }
    }
    // x->out copy stealing state (waves 4,5 only): 64 chunks of 64 float4 per block
    const bool steal = (w == 4) || (w == 5);
    int myC = (w == 5) ? 32 : 0;
    const int endC = steal ? ((w == 5) ? 64 : 32) : 0;
#define CPY1()                                                                         \
    {                                                                                  \
        size_t ii = (size_t)bl * 4096 + (size_t)myC * 64 + lane;                       \
        float4 vv = ((const float4*)xg)[ii];                                           \
        ((float4*)outg)[(ii >> 8) * 512 + (ii & 255)] = vv;                            \
        asm volatile("s_waitcnt vmcnt(0)" ::: "memory");                               \
        ++myC;                                                                         \
    }

    unsigned f0 = 0, f1 = 0;   // poller progress (w8)
    const int b16 = lane & 15, kq = lane >> 4;

    for (int s = 0; s < NSTEP; ++s) {
        if (w == 8) {
            int t0 = fam ? (s + 1) : s;
            int t1 = fam ? s : ((s >= 32) ? s : 0);
#define ADV(F, TGT, TB, FL)                                                            \
            while ((int)F < (TGT)) {                                                   \
                const unsigned* trow = (TB) + (size_t)F * 4096;                        \
                const unsigned* t0p = trow + (size_t)lane * 32;                        \
                const unsigned* t1p = trow + (size_t)(lane + 64) * 32;                 \
                while (__hip_atomic_load(t0p, __ATOMIC_RELAXED,                        \
                                         __HIP_MEMORY_SCOPE_AGENT) != 1u)              \
                    __builtin_amdgcn_s_sleep(4);                                       \
                while (__hip_atomic_load(t1p, __ATOMIC_RELAXED,                        \
                                         __HIP_MEMORY_SCOPE_AGENT) != 1u)              \
                    __builtin_amdgcn_s_sleep(4);                                       \
                ++F;                                                                   \
                if (lane == 0)                                                         \
                    __hip_atomic_store(&(FL), F, __ATOMIC_RELAXED,                     \
                                       __HIP_MEMORY_SCOPE_WORKGROUP);                  \
            }
            if (fam == 0) { ADV(f0, t0, tags0, flag0LDS) ADV(f1, t1, tags1, flag1LDS) }
            else          { ADV(f1, t1, tags1, flag1LDS) ADV(f0, t0, tags0, flag0LDS) }
#undef ADV
        } else {
            unsigned need0 = 0, need1 = 0;
            if (fam == 0) { if (m) need0 = (unsigned)s; else need1 = (s >= 32) ? (unsigned)s : 0u; }
            else          { if (m) need1 = (unsigned)s; else need0 = (unsigned)(s + 1); }
            if (need0) {
                while (__hip_atomic_load(&flag0LDS, __ATOMIC_RELAXED,
                                         __HIP_MEMORY_SCOPE_WORKGROUP) < need0) {
                    if (steal && myC < endC) { CPY1() } else __builtin_amdgcn_s_sleep(1);
                }
            }
            if (need1) {
                while (__hip_atomic_load(&flag1LDS, __ATOMIC_RELAXED,
                                         __HIP_MEMORY_SCOPE_WORKGROUP) < need1) {
                    if (steal && myC < endC) { CPY1() } else __builtin_amdgcn_s_sleep(1);
                }
            }
            asm volatile("" ::: "memory");

            const uchar* xsrc = fam ? (H0 + (size_t)(s + 1) * SLOT)
                              : (s < 32 ? seqb + (size_t)s * SLOT : H1 + (size_t)s * SLOT);
            const uchar* hsrc = fam ? (H1 + (size_t)s * SLOT) : (H0 + (size_t)s * SLOT);
            const uchar* asrc = m ? hsrc : xsrc;

            const uchar* ap = asrc + (size_t)lane * 32;
            uint4 A[8][2];
#pragma unroll
            for (int t = 0; t < 8; ++t) {
                A[t][0] = *(const uint4*)(ap + (size_t)(kh * 8 + t) * 2048);
                A[t][1] = *(const uint4*)(ap + (size_t)(kh * 8 + t) * 2048 + 16);
            }
            const uchar* bp0 = wlds + (size_t)((m * 4 + jp * 2) * 16 + kh * 8) * 1024 + lane * 16;
            const uchar* bp1 = bp0 + 16384;

            f32x4 aA0 = {0.f,0.f,0.f,0.f}, aA1 = {0.f,0.f,0.f,0.f};
            f32x4 aB0 = {0.f,0.f,0.f,0.f}, aB1 = {0.f,0.f,0.f,0.f};
#define MF(T)                                                                          \
            {                                                                          \
                uint4 alo = A[T][0], ahi = A[T][1];                                    \
                i8v av = {(int)alo.x, (int)alo.y, (int)alo.z, (int)alo.w,              \
                          (int)ahi.x, (int)ahi.y, (int)ahi.z, (int)ahi.w};             \
                uint4 b0 = *(const uint4*)(bp0 + (T) * 1024);                          \
                i8v bv0 = {(int)b0.x, (int)b0.y, (int)b0.z, (int)b0.w, 0, 0, 0, 0};    \
                uint4 b1 = *(const uint4*)(bp1 + (T) * 1024);                          \
                i8v bv1 = {(int)b1.x, (int)b1.y, (int)b1.z, (int)b1.w, 0, 0, 0, 0};    \
                if ((T) & 1) {                                                         \
                    aA1 = __builtin_amdgcn_mfma_scale_f32_16x16x128_f8f6f4(            \
                        av, bv0, aA1, 0, 4, 0, 127, (T) & 3,                           \
                        (int)((T) < 4 ? sw00 : sw01));                                 \
                    aB1 = __builtin_amdgcn_mfma_scale_f32_16x16x128_f8f6f4(            \
                        av, bv1, aB1, 0, 4, 0, 127, (T) & 3,                           \
                        (int)((T) < 4 ? sw10 : sw11));                                 \
                } else {                                                               \
                    aA0 = __builtin_amdgcn_mfma_scale_f32_16x16x128_f8f6f4(            \
                        av, bv0, aA0, 0, 4, 0, 127, (T) & 3,                           \
                        (int)((T) < 4 ? sw00 : sw01));                                 \
                    aB0 = __builtin_amdgcn_mfma_scale_f32_16x16x128_f8f6f4(            \
                        av, bv1, aB0, 0, 4, 0, 127, (T) & 3,                           \
                        (int)((T) < 4 ? sw10 : sw11));                                 \
                }                                                                      \
            }
            MF(0) MF(1) MF(2) MF(3) MF(4) MF(5) MF(6) MF(7)
#undef MF
            f32x4 rA = aA0 + aA1, rB = aB0 + aB1;
            const int slot = m * 2 + kh;
#pragma unroll
            for (int i = 0; i < 4; ++i) {
                gbuf[jp * 2 + 0][slot][kq * 4 + i][b16] = rA[i];
                gbuf[jp * 2 + 1][slot][kq * 4 + i][b16] = rB[i];
            }
        }
        __syncthreads();   // S1: all gbuf partials visible

        float gsum[2][4];
        if (w >= 6) {      // tails read gbuf before S2
            const int b = lane >> 2, flb = (lane & 3) * 2;
#pragma unroll
            for (int i = 0; i < 2; ++i) {
                const int f = wvoff + flb + i;
#pragma unroll
                for (int g = 0; g < 4; ++g)
                    gsum[i][g] = gbuf[g][0][b][f] + gbuf[g][1][b][f]
                               + gbuf[g][2][b][f] + gbuf[g][3][b][f];
            }
        }
        __syncthreads();   // S2: gbuf free for next iteration's writers

        if (w >= 6) {
            const int b = lane >> 2, flb = (lane & 3) * 2;
            u16 hb2 = 0;
            float hnv[2];
#pragma unroll
            for (int i = 0; i < 2; ++i) {
                float gv[4];
#pragma unroll
                for (int g = 0; g < 4; ++g) gv[g] = gsum[i][g] * 0.25f + bw[i][g];
                float cn = sigm(gv[1]) * cs[i] + sigm(gv[0]) * tanh_f(gv[2]);
                float hn = sigm(gv[3]) * tanh_f(cn);
                cs[i] = cn;
                hb2 |= (u16)(f2fp8(hn * 4.0f) << (8 * i));
                hnv[i] = hn;
            }
            const int wv = wvoff >> 3;
            *(u16*)((uchar*)&hs_st[b][wv] + flb) = hb2;
            asm volatile("s_waitcnt lgkmcnt(0)" ::: "memory");
            uchar* out = (fam ? H1 : H0) + (size_t)(s + 1) * SLOT;
            if (lane < 16) {
                const int kt0 = blf >> 3, sub = (blf & 7) >> 1, byte0 = (blf & 1) * 16;
                size_t o = (size_t)kt0 * 2048 + (size_t)(lane + 16 * sub) * 32 + byte0 + wvoff;
                __hip_atomic_store((u64*)(out + o), hs_st[lane][wv],
                                   __ATOMIC_RELAXED, __HIP_MEMORY_SCOPE_AGENT);
            }
            asm volatile("s_waitcnt vmcnt(0)" ::: "memory");   // own h-half acked at L3
            if (w == 6) {
                if (lane == 0)
                    __hip_atomic_store(&w6done, (unsigned)(s + 1),
                                       __ATOMIC_RELAXED, __HIP_MEMORY_SCOPE_WORKGROUP);
            } else {
                if (lane == 0) {
                    while (__hip_atomic_load(&w6done, __ATOMIC_RELAXED,
                                             __HIP_MEMORY_SCOPE_WORKGROUP) < (unsigned)(s + 1))
                        ;   // short LDS spin: w6 drains concurrently
                    unsigned* tg = (fam ? tags1 : tags0) + (size_t)s * 4096 + (size_t)blf * 32;
                    __hip_atomic_store(tg, 1u, __ATOMIC_RELAXED, __HIP_MEMORY_SCOPE_AGENT);
                }
            }
            if (fam && s >= 31) {   // L1 outputs (off the notify path)
                unsigned pk = (unsigned)f2b(hnv[0]) | ((unsigned)f2b(hnv[1]) << 16);
                *(unsigned*)(seqout + (size_t)(s - 31) * 16 * FDIM
                             + (size_t)b * FDIM + blf * 16 + wvoff + flb) = pk;
            }
        }
    }
    // sweep leftover copy chunks
    if (steal) while (myC < endC) CPY1()
#undef CPY1
}

// ---------------- output 1x1 conv into bottom half ----------------
__global__ __launch_bounds__(256) void k_convout(const u16* __restrict__ seqout,
                                                 const float* __restrict__ w_out,
                                                 const float* __restrict__ b_out,
                                                 float* __restrict__ out) {
    int s = blockIdx.x >> 4, b = blockIdx.x & 15;
    __shared__ float srow[2048];
    int tid = threadIdx.x;
    for (int i = tid; i < 2048; i += 256) srow[i] = b2f(seqout[((size_t)s * 16 + b) * FDIM + i]);
    __syncthreads();
    int o = tid;
    float bo = b_out[o];
    float wreg[64];
#pragma unroll
    for (int cb = 0; cb < 64; ++cb) wreg[cb] = w_out[o * 64 + cb];
    for (int w4 = 0; w4 < 8; ++w4) {
        float ac0 = bo, ac1 = bo, ac2 = bo, ac3 = bo;
#pragma unroll
        for (int cb = 0; cb < 64; ++cb) {
            float wv = wreg[cb];
            ac0 += srow[(w4 * 4 + 0) * 64 + cb] * wv;
            ac1 += srow[(w4 * 4 + 1) * 64 + cb] * wv;
            ac2 += srow[(w4 * 4 + 2) * 64 + cb] * wv;
            ac3 += srow[(w4 * 4 + 3) * 64 + cb] * wv;
        }
        float4 v; v.x = ac0; v.y = ac1; v.z = ac2; v.w = ac3;
        *(float4*)&out[(((size_t)b * 256 + o) * 64 + 32 + s) * 32 + w4 * 4] = v;
    }
}

extern "C" void kernel_launch(void* const* d_in, const int* in_sizes, int n_in,
                              void* d_out, int out_size, void* d_ws, size_t ws_size,
                              hipStream_t stream) {
    const float* x    = (const float*)d_in[0];
    const float* w_in = (const float*)d_in[1];
    const float* b_in = (const float*)d_in[2];
    const float* Wih0 = (const float*)d_in[3];
    const float* Whh0 = (const float*)d_in[4];
    const float* bih0 = (const float*)d_in[5];
    const float* bhh0 = (const float*)d_in[6];
    const float* Wih1 = (const float*)d_in[7];
    const float* Whh1 = (const float*)d_in[8];
    const float* bih1 = (const float*)d_in[9];
    const float* bhh1 = (const float*)d_in[10];
    const float* wout = (const float*)d_in[11];
    const float* bout = (const float*)d_in[12];
    float* out = (float*)d_out;
    char* ws = (char*)d_ws;
    const size_t BF = (size_t)16 * FDIM;

    size_t off = 0;
    uchar* seqb = (uchar*)(ws + off); off += (size_t)32 * SLOT;             // 1 MiB
    u16* seqout = (u16*)(ws + off); off += (size_t)32 * BF * 2;             // 2 MiB
    uchar* H0 = (uchar*)(ws + off); off += (size_t)64 * SLOT;               // 2 MiB
    uchar* H1 = (uchar*)(ws + off); off += (size_t)64 * SLOT;               // 2 MiB
    off = (off + 127) & ~(size_t)127;
    unsigned* tags0 = (unsigned*)(ws + off); size_t tagoff = off;
    off += (size_t)NSTEP * 4096 * 4;                           // 63 rows x 128 tags x 128B
    unsigned* tags1 = (unsigned*)(ws + off);
    off += (size_t)NSTEP * 4096 * 4;

    // zero: H0 slot0, H1 slot0, both tag arrays (in-graph, every replay)
    hipMemsetAsync(H0, 0, SLOT, stream);
    hipMemsetAsync(H1, 0, SLOT, stream);
    hipMemsetAsync(ws + tagoff, 0, off - tagoff, stream);

    k_seqprep<<<512, 256, 0, stream>>>(x, w_in, b_in, seqb);
    k_lstm<<<NBLK, 576, 0, stream>>>(Wih0, Whh0, Wih1, Whh1,
                                     bih0, bhh0, bih1, bhh1,
                                     seqb, H0, H1, seqout, tags0, tags1, x, out);
    k_convout<<<512, 256, 0, stream>>>(seqout, wout, bout, out);
}

// Round 15
// 583.814 us; speedup vs baseline: 2.6681x; 1.0006x over previous
//
#include <hip/hip_runtime.h>
#include <hip/hip_bf16.h>

typedef unsigned short u16;
typedef unsigned char uchar;
typedef unsigned long long u64;
typedef float f32x4 __attribute__((ext_vector_type(4)));
typedef int i8v __attribute__((ext_vector_type(8)));

#define FDIM 2048
#define NBLK 256
#define NSTEP 63
#define SLOT 32768   // bytes per h slot (16 x 2048 fp8)

__device__ __forceinline__ u16 f2b(float x) {
    __hip_bfloat16 h = __float2bfloat16(x);
    return __builtin_bit_cast(u16, h);
}
__device__ __forceinline__ float b2f(u16 u) {
    __hip_bfloat16 h = __builtin_bit_cast(__hip_bfloat16, u);
    return __bfloat162float(h);
}
__device__ __forceinline__ float sigm(float x) { return 1.0f / (1.0f + __expf(-x)); }
__device__ __forceinline__ float tanh_f(float x) { return 1.0f - 2.0f / (__expf(2.0f * x) + 1.0f); }

// OCP e4m3 encode (RNE), saturate to 448.
__device__ __forceinline__ unsigned f2fp8(float x) {
    unsigned u = __builtin_bit_cast(unsigned, x);
    unsigned s = (u >> 24) & 0x80u;
    unsigned mag = u & 0x7fffffffu;
    if (mag >= 0x43E80000u) return s | 0x7Eu;
    int e = (int)(mag >> 23) - 127;
    if (e >= -6) {
        unsigned m = mag + 0x7FFFFu + ((mag >> 20) & 1u);
        unsigned e8 = (m >> 23) - 127 + 7;
        unsigned m3 = (m >> 20) & 7u;
        if (e8 >= 16u) return s | 0x7Eu;
        return s | (e8 << 3) | m3;
    }
    float ax = __builtin_bit_cast(float, mag);
    int d = (int)__builtin_rintf(ax * 512.0f);
    return s | (unsigned)d;
}

// e2m1 (fp4) quantize (|v|<=6 after scaling)
__device__ __forceinline__ unsigned q_e2m1(float v) {
    unsigned s = (v < 0.f) ? 8u : 0u;
    float a = fabsf(v);
    unsigned q;
    if (a < 0.25f) q = 0;
    else if (a < 0.75f) q = 1;
    else if (a < 1.25f) q = 2;
    else if (a < 1.75f) q = 3;
    else if (a < 2.5f)  q = 4;
    else if (a < 3.5f)  q = 5;
    else if (a < 5.0f)  q = 6;
    else q = 7;
    return s | q;
}

// ---------------- input 1x1 conv -> seq slots in MFMA-FRAGMENT layout, fp8 (x4) ----------------
__global__ __launch_bounds__(256) void k_seqprep(const float* __restrict__ x,
                                                 const float* __restrict__ w_in,
                                                 const float* __restrict__ b_in,
                                                 uchar* __restrict__ seqb) {
    int h = blockIdx.x >> 4, b = blockIdx.x & 15;
    __shared__ float xs[256][32];
    __shared__ float wl[64][257];
    int tid = threadIdx.x;
    for (int i = tid; i < 256 * 32; i += 256) {
        int c = i >> 5, w = i & 31;
        xs[c][w] = x[(((size_t)b * 256 + c) * 32 + h) * 32 + w];
    }
    for (int i = tid; i < 64 * 256; i += 256) {
        int cb = i >> 8, c = i & 255;
        wl[cb][c] = w_in[i];
    }
    __syncthreads();
    int w = (tid * 8) >> 6, cb0 = (tid * 8) & 63;
    float acc[8];
#pragma unroll
    for (int j = 0; j < 8; ++j) acc[j] = b_in[cb0 + j];
    for (int c = 0; c < 256; ++c) {
        float xv = xs[c][w];
#pragma unroll
        for (int j = 0; j < 8; ++j) acc[j] += xv * wl[cb0 + j][c];
    }
    unsigned lo = 0, hi2 = 0;
#pragma unroll
    for (int j = 0; j < 4; ++j) lo |= f2fp8(acc[j] * 4.0f) << (j * 8);
#pragma unroll
    for (int j = 0; j < 4; ++j) hi2 |= f2fp8(acc[4 + j] * 4.0f) << (j * 8);
    int kt = tid >> 4, kq = (tid >> 2) & 3, e0 = (tid & 3) * 8;
    uchar* dst = seqb + (size_t)h * SLOT + (size_t)kt * 2048 + (size_t)(b + 16 * kq) * 32 + e0;
    *(uint2*)dst = make_uint2(lo, hi2);
}

// ---------------- persistent LSTM: all-in-one ----------------
// Prologue: each block packs its own fp32 weights -> fp4 MX in LDS.
// Blocks 0..127 = L0 family; 128..255 = L1 family. 9 waves: w0..7 compute
// (jp = w&1, kh = (w>>1)&1, m = w>>2); w8 poller; w6/w7 tails (single tag via w6done);
// w4/w5 steal x->out copy chunks ONLY during ENCODE waits (decode stays jitter-free);
// leftovers swept post-loop without per-chunk drains.
__global__ __launch_bounds__(576, 1) void k_lstm(const float* __restrict__ Wih0,
                                                 const float* __restrict__ Whh0,
                                                 const float* __restrict__ Wih1,
                                                 const float* __restrict__ Whh1,
                                                 const float* __restrict__ bih0,
                                                 const float* __restrict__ bhh0,
                                                 const float* __restrict__ bih1,
                                                 const float* __restrict__ bhh1,
                                                 const uchar* __restrict__ seqb,
                                                 uchar* __restrict__ H0, uchar* __restrict__ H1,
                                                 u16* __restrict__ seqout,
                                                 unsigned* __restrict__ tags0,
                                                 unsigned* __restrict__ tags1,
                                                 const float* __restrict__ xg,
                                                 float* __restrict__ outg) {
    __shared__ uchar wlds[131072];            // [m][jt][kt][lane*16] fp4 packed
    __shared__ uchar sclLDS[8192];            // [m][jt][lane]x16 kt scale bytes
    __shared__ float gbuf[4][4][16][16];      // [gate][m*2+kh][b][feat] partials (16KB)
    __shared__ u64 hs_st[16][2];
    __shared__ unsigned flag0LDS, flag1LDS, w6done;
    const int tid = threadIdx.x, lane = tid & 63, w = tid >> 6;
    const int jp = w & 1, kh = (w >> 1) & 1, m = w >> 2;  // valid for w<8
    const int bl = blockIdx.x;
    const int fam = bl >> 7, blf = bl & 127;

    // ---- prologue: pack this block's weights fp32 -> fp4 MX directly into LDS ----
    {
        const float* srcA = fam ? Wih1 : Wih0;   // mm = 0
        const float* srcB = fam ? Whh1 : Whh0;   // mm = 1
        for (int e = tid; e < 8192; e += 576) {
            int l = e & 63, kt = (e >> 6) & 15, jt = (e >> 10) & 3, mm = e >> 12;
            const float* src = mm ? srcB : srcA;
            const float* p = src + (size_t)(jt * 2048 + blf * 16 + (l & 15)) * 2048
                           + kt * 128 + (l >> 4) * 32;
            float v[32];
#pragma unroll
            for (int j = 0; j < 8; ++j) {
                float4 q = *(const float4*)(p + j * 4);
                v[j * 4 + 0] = q.x; v[j * 4 + 1] = q.y;
                v[j * 4 + 2] = q.z; v[j * 4 + 3] = q.w;
            }
            float mx = 0.f;
#pragma unroll
            for (int ei = 0; ei < 32; ++ei) mx = fmaxf(mx, fabsf(v[ei]));
            int ee = -127;
            if (mx > 0.f) {
                ee = (int)ceilf(log2f(mx * (1.0f / 6.0f)));
                if (ee < -127) ee = -127;
                if (ee > 127) ee = 127;
            }
            float inv = exp2f((float)(-ee));
            unsigned wd[4];
#pragma unroll
            for (int d = 0; d < 4; ++d) {
                unsigned acc = 0;
#pragma unroll
                for (int bi = 0; bi < 4; ++bi) {
                    float v0 = v[d * 8 + 2 * bi] * inv;
                    float v1 = v[d * 8 + 2 * bi + 1] * inv;
                    acc |= (q_e2m1(v0) << (bi * 8)) | (q_e2m1(v1) << (bi * 8 + 4));
                }
                wd[d] = acc;
            }
            *(uint4*)(wlds + (size_t)e * 16) = make_uint4(wd[0], wd[1], wd[2], wd[3]);
            sclLDS[(size_t)((mm * 4 + jt) * 64 + l) * 16 + kt] = (uchar)(ee + 127);
        }
    }
    if (tid == 0) { flag0LDS = 0; flag1LDS = 0; w6done = 0; }
    __syncthreads();

    unsigned sw00 = 0, sw01 = 0, sw10 = 0, sw11 = 0;
    if (w < 8) {
        const uchar* sbase = sclLDS + (size_t)((m * 4 + jp * 2) * 64 + lane) * 16;
        uint4 s0 = *(const uint4*)(sbase);
        uint4 s1 = *(const uint4*)(sbase + 1024);
        sw00 = kh ? s0.z : s0.x; sw01 = kh ? s0.w : s0.y;
        sw10 = kh ? s1.z : s1.x; sw11 = kh ? s1.w : s1.y;
    }
    // tail state (w6: local features 0..7, w7: 8..15); 2 (b,f) pairs per lane
    float bw[2][4];
    float cs[2] = {0.f, 0.f};
    const int wvoff = (w == 7) ? 8 : 0;
    if (w >= 6) {
        const int flb = (lane & 3) * 2;
        const float* bi_ = fam ? bih1 : bih0;
        const float* bh_ = fam ? bhh1 : bhh0;
#pragma unroll
        for (int i = 0; i < 2; ++i) {
            int col = blf * 16 + wvoff + flb + i;
#pragma unroll
            for (int g = 0; g < 4; ++g)
                bw[i][g] = bi_[g * FDIM + col] + bh_[g * FDIM + col];
        }
    }
    // x->out copy stealing state (waves 4,5): 64 chunks of 64 float4 per block
    const bool steal = (w == 4) || (w == 5);
    int myC = (w == 5) ? 32 : 0;
    const int endC = steal ? ((w == 5) ? 64 : 32) : 0;
// in-wait variant: drains after each chunk so the wave can respond to the flag fast
#define CPY1()                                                                         \
    {                                                                                  \
        size_t ii = (size_t)bl * 4096 + (size_t)myC * 64 + lane;                       \
        float4 vv = ((const float4*)xg)[ii];                                           \
        ((float4*)outg)[(ii >> 8) * 512 + (ii & 255)] = vv;                            \
        asm volatile("s_waitcnt vmcnt(0)" ::: "memory");                               \
        ++myC;                                                                         \
    }
// sweep variant: no per-chunk drain (kernel end drains implicitly)
#define CPYF()                                                                         \
    {                                                                                  \
        size_t ii = (size_t)bl * 4096 + (size_t)myC * 64 + lane;                       \
        float4 vv = ((const float4*)xg)[ii];                                           \
        ((float4*)outg)[(ii >> 8) * 512 + (ii & 255)] = vv;                            \
        ++myC;                                                                         \
    }

    unsigned f0 = 0, f1 = 0;   // poller progress (w8)
    const int b16 = lane & 15, kq = lane >> 4;

    for (int s = 0; s < NSTEP; ++s) {
        if (w == 8) {
            int t0 = fam ? (s + 1) : s;
            int t1 = fam ? s : ((s >= 32) ? s : 0);
#define ADV(F, TGT, TB, FL)                                                            \
            while ((int)F < (TGT)) {                                                   \
                const unsigned* trow = (TB) + (size_t)F * 4096;                        \
                const unsigned* t0p = trow + (size_t)lane * 32;                        \
                const unsigned* t1p = trow + (size_t)(lane + 64) * 32;                 \
                while (__hip_atomic_load(t0p, __ATOMIC_RELAXED,                        \
                                         __HIP_MEMORY_SCOPE_AGENT) != 1u)              \
                    __builtin_amdgcn_s_sleep(4);                                       \
                while (__hip_atomic_load(t1p, __ATOMIC_RELAXED,                        \
                                         __HIP_MEMORY_SCOPE_AGENT) != 1u)              \
                    __builtin_amdgcn_s_sleep(4);                                       \
                ++F;                                                                   \
                if (lane == 0)                                                         \
                    __hip_atomic_store(&(FL), F, __ATOMIC_RELAXED,                     \
                                       __HIP_MEMORY_SCOPE_WORKGROUP);                  \
            }
            if (fam == 0) { ADV(f0, t0, tags0, flag0LDS) ADV(f1, t1, tags1, flag1LDS) }
            else          { ADV(f1, t1, tags1, flag1LDS) ADV(f0, t0, tags0, flag0LDS) }
#undef ADV
        } else {
            unsigned need0 = 0, need1 = 0;
            if (fam == 0) { if (m) need0 = (unsigned)s; else need1 = (s >= 32) ? (unsigned)s : 0u; }
            else          { if (m) need1 = (unsigned)s; else need0 = (unsigned)(s + 1); }
            const bool canSteal = steal && (s < 32);   // encode only: decode stays jitter-free
            if (need0) {
                while (__hip_atomic_load(&flag0LDS, __ATOMIC_RELAXED,
                                         __HIP_MEMORY_SCOPE_WORKGROUP) < need0) {
                    if (canSteal && myC < endC) { CPY1() } else __builtin_amdgcn_s_sleep(1);
                }
            }
            if (need1) {
                while (__hip_atomic_load(&flag1LDS, __ATOMIC_RELAXED,
                                         __HIP_MEMORY_SCOPE_WORKGROUP) < need1) {
                    if (canSteal && myC < endC) { CPY1() } else __builtin_amdgcn_s_sleep(1);
                }
            }
            asm volatile("" ::: "memory");

            const uchar* xsrc = fam ? (H0 + (size_t)(s + 1) * SLOT)
                              : (s < 32 ? seqb + (size_t)s * SLOT : H1 + (size_t)s * SLOT);
            const uchar* hsrc = fam ? (H1 + (size_t)s * SLOT) : (H0 + (size_t)s * SLOT);
            const uchar* asrc = m ? hsrc : xsrc;

            const uchar* ap = asrc + (size_t)lane * 32;
            uint4 A[8][2];
#pragma unroll
            for (int t = 0; t < 8; ++t) {
                A[t][0] = *(const uint4*)(ap + (size_t)(kh * 8 + t) * 2048);
                A[t][1] = *(const uint4*)(ap + (size_t)(kh * 8 + t) * 2048 + 16);
            }
            const uchar* bp0 = wlds + (size_t)((m * 4 + jp * 2) * 16 + kh * 8) * 1024 + lane * 16;
            const uchar* bp1 = bp0 + 16384;

            f32x4 aA0 = {0.f,0.f,0.f,0.f}, aA1 = {0.f,0.f,0.f,0.f};
            f32x4 aB0 = {0.f,0.f,0.f,0.f}, aB1 = {0.f,0.f,0.f,0.f};
#define MF(T)                                                                          \
            {                                                                          \
                uint4 alo = A[T][0], ahi = A[T][1];                                    \
                i8v av = {(int)alo.x, (int)alo.y, (int)alo.z, (int)alo.w,              \
                          (int)ahi.x, (int)ahi.y, (int)ahi.z, (int)ahi.w};             \
                uint4 b0 = *(const uint4*)(bp0 + (T) * 1024);                          \
                i8v bv0 = {(int)b0.x, (int)b0.y, (int)b0.z, (int)b0.w, 0, 0, 0, 0};    \
                uint4 b1 = *(const uint4*)(bp1 + (T) * 1024);                          \
                i8v bv1 = {(int)b1.x, (int)b1.y, (int)b1.z, (int)b1.w, 0, 0, 0, 0};    \
                if ((T) & 1) {                                                         \
                    aA1 = __builtin_amdgcn_mfma_scale_f32_16x16x128_f8f6f4(            \
                        av, bv0, aA1, 0, 4, 0, 127, (T) & 3,                           \
                        (int)((T) < 4 ? sw00 : sw01));                                 \
                    aB1 = __builtin_amdgcn_mfma_scale_f32_16x16x128_f8f6f4(            \
                        av, bv1, aB1, 0, 4, 0, 127, (T) & 3,                           \
                        (int)((T) < 4 ? sw10 : sw11));                                 \
                } else {                                                               \
                    aA0 = __builtin_amdgcn_mfma_scale_f32_16x16x128_f8f6f4(            \
                        av, bv0, aA0, 0, 4, 0, 127, (T) & 3,                           \
                        (int)((T) < 4 ? sw00 : sw01));                                 \
                    aB0 = __builtin_amdgcn_mfma_scale_f32_16x16x128_f8f6f4(            \
                        av, bv1, aB0, 0, 4, 0, 127, (T) & 3,                           \
                        (int)((T) < 4 ? sw10 : sw11));                                 \
                }                                                                      \
            }
            MF(0) MF(1) MF(2) MF(3) MF(4) MF(5) MF(6) MF(7)
#undef MF
            f32x4 rA = aA0 + aA1, rB = aB0 + aB1;
            const int slot = m * 2 + kh;
#pragma unroll
            for (int i = 0; i < 4; ++i) {
                gbuf[jp * 2 + 0][slot][kq * 4 + i][b16] = rA[i];
                gbuf[jp * 2 + 1][slot][kq * 4 + i][b16] = rB[i];
            }
        }
        __syncthreads();   // S1: all gbuf partials visible

        float gsum[2][4];
        if (w >= 6) {      // tails read gbuf before S2
            const int b = lane >> 2, flb = (lane & 3) * 2;
#pragma unroll
            for (int i = 0; i < 2; ++i) {
                const int f = wvoff + flb + i;
#pragma unroll
                for (int g = 0; g < 4; ++g)
                    gsum[i][g] = gbuf[g][0][b][f] + gbuf[g][1][b][f]
                               + gbuf[g][2][b][f] + gbuf[g][3][b][f];
            }
        }
        __syncthreads();   // S2: gbuf free for next iteration's writers

        if (w >= 6) {
            const int b = lane >> 2, flb = (lane & 3) * 2;
            u16 hb2 = 0;
            float hnv[2];
#pragma unroll
            for (int i = 0; i < 2; ++i) {
                float gv[4];
#pragma unroll
                for (int g = 0; g < 4; ++g) gv[g] = gsum[i][g] * 0.25f + bw[i][g];
                float cn = sigm(gv[1]) * cs[i] + sigm(gv[0]) * tanh_f(gv[2]);
                float hn = sigm(gv[3]) * tanh_f(cn);
                cs[i] = cn;
                hb2 |= (u16)(f2fp8(hn * 4.0f) << (8 * i));
                hnv[i] = hn;
            }
            const int wv = wvoff >> 3;
            *(u16*)((uchar*)&hs_st[b][wv] + flb) = hb2;
            asm volatile("s_waitcnt lgkmcnt(0)" ::: "memory");
            uchar* out = (fam ? H1 : H0) + (size_t)(s + 1) * SLOT;
            if (lane < 16) {
                const int kt0 = blf >> 3, sub = (blf & 7) >> 1, byte0 = (blf & 1) * 16;
                size_t o = (size_t)kt0 * 2048 + (size_t)(lane + 16 * sub) * 32 + byte0 + wvoff;
                __hip_atomic_store((u64*)(out + o), hs_st[lane][wv],
                                   __ATOMIC_RELAXED, __HIP_MEMORY_SCOPE_AGENT);
            }
            asm volatile("s_waitcnt vmcnt(0)" ::: "memory");   // own h-half acked at L3
            if (w == 6) {
                if (lane == 0)
                    __hip_atomic_store(&w6done, (unsigned)(s + 1),
                                       __ATOMIC_RELAXED, __HIP_MEMORY_SCOPE_WORKGROUP);
            } else {
                if (lane == 0) {
                    while (__hip_atomic_load(&w6done, __ATOMIC_RELAXED,
                                             __HIP_MEMORY_SCOPE_WORKGROUP) < (unsigned)(s + 1))
                        ;   // short LDS spin: w6 drains concurrently
                    unsigned* tg = (fam ? tags1 : tags0) + (size_t)s * 4096 + (size_t)blf * 32;
                    __hip_atomic_store(tg, 1u, __ATOMIC_RELAXED, __HIP_MEMORY_SCOPE_AGENT);
                }
            }
            if (fam && s >= 31) {   // L1 outputs (off the notify path)
                unsigned pk = (unsigned)f2b(hnv[0]) | ((unsigned)f2b(hnv[1]) << 16);
                *(unsigned*)(seqout + (size_t)(s - 31) * 16 * FDIM
                             + (size_t)b * FDIM + blf * 16 + wvoff + flb) = pk;
            }
        }
    }
    // sweep leftover copy chunks (no per-chunk drain; kernel end drains)
    if (steal) while (myC < endC) CPYF()
#undef CPY1
#undef CPYF
}

// ---------------- output 1x1 conv into bottom half ----------------
__global__ __launch_bounds__(256) void k_convout(const u16* __restrict__ seqout,
                                                 const float* __restrict__ w_out,
                                                 const float* __restrict__ b_out,
                                                 float* __restrict__ out) {
    int s = blockIdx.x >> 4, b = blockIdx.x & 15;
    __shared__ float srow[2048];
    int tid = threadIdx.x;
    for (int i = tid; i < 2048; i += 256) srow[i] = b2f(seqout[((size_t)s * 16 + b) * FDIM + i]);
    __syncthreads();
    int o = tid;
    float bo = b_out[o];
    float wreg[64];
#pragma unroll
    for (int cb = 0; cb < 64; ++cb) wreg[cb] = w_out[o * 64 + cb];
    for (int w4 = 0; w4 < 8; ++w4) {
        float ac0 = bo, ac1 = bo, ac2 = bo, ac3 = bo;
#pragma unroll
        for (int cb = 0; cb < 64; ++cb) {
            float wv = wreg[cb];
            ac0 += srow[(w4 * 4 + 0) * 64 + cb] * wv;
            ac1 += srow[(w4 * 4 + 1) * 64 + cb] * wv;
            ac2 += srow[(w4 * 4 + 2) * 64 + cb] * wv;
            ac3 += srow[(w4 * 4 + 3) * 64 + cb] * wv;
        }
        float4 v; v.x = ac0; v.y = ac1; v.z = ac2; v.w = ac3;
        *(float4*)&out[(((size_t)b * 256 + o) * 64 + 32 + s) * 32 + w4 * 4] = v;
    }
}

extern "C" void kernel_launch(void* const* d_in, const int* in_sizes, int n_in,
                              void* d_out, int out_size, void* d_ws, size_t ws_size,
                              hipStream_t stream) {
    const float* x    = (const float*)d_in[0];
    const float* w_in = (const float*)d_in[1];
    const float* b_in = (const float*)d_in[2];
    const float* Wih0 = (const float*)d_in[3];
    const float* Whh0 = (const float*)d_in[4];
    const float* bih0 = (const float*)d_in[5];
    const float* bhh0 = (const float*)d_in[6];
    const float* Wih1 = (const float*)d_in[7];
    const float* Whh1 = (const float*)d_in[8];
    const float* bih1 = (const float*)d_in[9];
    const float* bhh1 = (const float*)d_in[10];
    const float* wout = (const float*)d_in[11];
    const float* bout = (const float*)d_in[12];
    float* out = (float*)d_out;
    char* ws = (char*)d_ws;
    const size_t BF = (size_t)16 * FDIM;

    size_t off = 0;
    uchar* seqb = (uchar*)(ws + off); off += (size_t)32 * SLOT;             // 1 MiB
    u16* seqout = (u16*)(ws + off); off += (size_t)32 * BF * 2;             // 2 MiB
    uchar* H0 = (uchar*)(ws + off); off += (size_t)64 * SLOT;               // 2 MiB
    uchar* H1 = (uchar*)(ws + off); off += (size_t)64 * SLOT;               // 2 MiB
    off = (off + 127) & ~(size_t)127;
    unsigned* tags0 = (unsigned*)(ws + off); size_t tagoff = off;
    off += (size_t)NSTEP * 4096 * 4;                           // 63 rows x 128 tags x 128B
    unsigned* tags1 = (unsigned*)(ws + off);
    off += (size_t)NSTEP * 4096 * 4;

    // zero: H0 slot0, H1 slot0, both tag arrays (in-graph, every replay)
    hipMemsetAsync(H0, 0, SLOT, stream);
    hipMemsetAsync(H1, 0, SLOT, stream);
    hipMemsetAsync(ws + tagoff, 0, off - tagoff, stream);

    k_seqprep<<<512, 256, 0, stream>>>(x, w_in, b_in, seqb);
    k_lstm<<<NBLK, 576, 0, stream>>>(Wih0, Whh0, Wih1, Whh1,
                                     bih0, bhh0, bih1, bhh1,
                                     seqb, H0, H1, seqout, tags0, tags1, x, out);
    k_convout<<<512, 256, 0, stream>>>(seqout, wout, bout, out);
}